// Round 6
// baseline (656.444 us; speedup 1.0000x reference)
//
#include <hip/hip_runtime.h>

#define C_ 256
#define D_ 56
#define N_ 64
#define M_ 3584     // rows per channel (N*56), same both stages since H==W
#define DD_ 3136    // 56*56
#define PL_ 200704  // per-channel plane = M_*56
#define NS_ITERS 16
#define TG 8        // tiles per transpose block

typedef __attribute__((ext_vector_type(8))) short v8s;
typedef __attribute__((ext_vector_type(8))) _Float16 v8h;
typedef __attribute__((ext_vector_type(4))) _Float16 v4h;
typedef __attribute__((ext_vector_type(4))) float v4f;

__device__ __forceinline__ unsigned short f2bf(float f) {
  union { float f; unsigned u; } x; x.f = f;
  unsigned r = x.u + 0x7FFFu + ((x.u >> 16) & 1u);
  return (unsigned short)(r >> 16);
}
__device__ __forceinline__ float bf2f(unsigned short h) {
  union { unsigned u; float f; } x; x.u = ((unsigned)h) << 16;
  return x.f;
}

// x (N,H,W,C) -> A (C, n*56+w, h)  — pipelined: TG tiles/block, reg-staged loads
__global__ __launch_bounds__(256) void k_tin(const float* __restrict__ x, float* __restrict__ A) {
  int b = blockIdx.x;
  int cchunk = b & 3, g = b >> 2;
  int c0 = cchunk * 64;
  __shared__ float t[56][65];
  int tid = threadIdx.x;
  float4 regs[4], nxt[4];
  {
    int nw = g*TG;
    int n = nw/56, w = nw%56;
    const float4* xp4 = (const float4*)(x + ((size_t)n*3136 + w)*256 + c0);
    #pragma unroll
    for (int it = 0; it < 4; ++it) {
      int i4 = tid + 256*it;
      if (i4 < 896) { int h = i4 >> 4, cg = i4 & 15; regs[it] = xp4[(size_t)h*3584 + cg]; }
    }
  }
  for (int tt = 0; tt < TG; ++tt) {
    int nw = g*TG + tt;
    if (tt+1 < TG) {           // issue next tile's loads (latency hides under store phase)
      int nw2 = nw + 1;
      int n2 = nw2/56, w2 = nw2%56;
      const float4* xq = (const float4*)(x + ((size_t)n2*3136 + w2)*256 + c0);
      #pragma unroll
      for (int it = 0; it < 4; ++it) {
        int i4 = tid + 256*it;
        if (i4 < 896) { int h = i4 >> 4, cg = i4 & 15; nxt[it] = xq[(size_t)h*3584 + cg]; }
      }
    }
    #pragma unroll
    for (int it = 0; it < 4; ++it) {
      int i4 = tid + 256*it;
      if (i4 < 896) {
        int h = i4 >> 4, cg = i4 & 15;
        t[h][4*cg+0] = regs[it].x; t[h][4*cg+1] = regs[it].y;
        t[h][4*cg+2] = regs[it].z; t[h][4*cg+3] = regs[it].w;
      }
    }
    __syncthreads();
    float* Ap = A + (size_t)c0*PL_ + (size_t)nw*56;
    #pragma unroll
    for (int it = 0; it < 4; ++it) {
      int i4 = tid + 256*it;
      if (i4 < 896) {
        int cc = i4 / 14, hg = (i4 % 14) * 4;
        float4 o;
        o.x = t[hg+0][cc]; o.y = t[hg+1][cc]; o.z = t[hg+2][cc]; o.w = t[hg+3][cc];
        *(float4*)&Ap[(size_t)cc*PL_ + hg] = o;
      }
    }
    __syncthreads();
    #pragma unroll
    for (int it = 0; it < 4; ++it) regs[it] = nxt[it];
  }
}

// ---------- fp16-split MFMA helpers ----------
__device__ __forceinline__ void mm_split_h(const _Float16 (*Ah)[72], const _Float16 (*Al)[72],
                                           const _Float16 (*Bh)[72], const _Float16 (*Bl)[72],
                                           int w, int lr, int lq, v4f (&acc)[4]) {
  v8h ah[2], al[2], bh[4][2], bl[4][2];
  #pragma unroll
  for (int s = 0; s < 2; ++s) {
    int kb = 32*s + 8*lq;
    ah[s] = *(const v8h*)&Ah[16*w + lr][kb];
    al[s] = *(const v8h*)&Al[16*w + lr][kb];
    #pragma unroll
    for (int jt = 0; jt < 4; ++jt) {
      bh[jt][s] = *(const v8h*)&Bh[16*jt + lr][kb];
      bl[jt][s] = *(const v8h*)&Bl[16*jt + lr][kb];
    }
  }
  #pragma unroll
  for (int jt = 0; jt < 4; ++jt) {
    #pragma unroll
    for (int s = 0; s < 2; ++s) {
      acc[jt] = __builtin_amdgcn_mfma_f32_16x16x32_f16(ah[s], bh[jt][s], acc[jt], 0, 0, 0);
      acc[jt] = __builtin_amdgcn_mfma_f32_16x16x32_f16(ah[s], bl[jt][s], acc[jt], 0, 0, 0);
      acc[jt] = __builtin_amdgcn_mfma_f32_16x16x32_f16(al[s], bh[jt][s], acc[jt], 0, 0, 0);
    }
  }
}

__device__ __forceinline__ void store_split_h(_Float16 (*H)[72], _Float16 (*L)[72],
                                              int w, int lr, int lq, const v4f (&val)[4]) {
  #pragma unroll
  for (int jt = 0; jt < 4; ++jt) {
    #pragma unroll
    for (int e = 0; e < 4; ++e) {
      int i = 16*w + 4*lq + e, j = 16*jt + lr;
      float v = val[jt][e];
      _Float16 h = (_Float16)v;
      H[i][j] = h;
      L[i][j] = (_Float16)(v - (float)h);
    }
  }
}

// Fused: raw column-sum (fp32 exact, in-register) + raw second moment via split-bf16 MFMA.
__global__ __launch_bounds__(256) void k_stats(const float* __restrict__ in,
                                               float* __restrict__ muPart,
                                               float* __restrict__ covPart) {
  int b = blockIdx.x;
  int c = b >> 3, s = b & 7;
  const float* p = in + (size_t)c*PL_ + (size_t)(s*448)*56;
  __shared__ __align__(16) char lds[18432];
  unsigned short (*At)[72]  = (unsigned short(*)[72])lds;
  unsigned short (*Alt)[72] = (unsigned short(*)[72])(lds + 9216);
  float (*Qbuf)[66] = (float(*)[66])lds;
  float (*red2)[60] = (float(*)[60])lds;
  int tid = threadIdx.x;
  int cg = tid % 14, rg = tid / 14;
  bool act = tid < 224;
  float4 colsum = make_float4(0.f, 0.f, 0.f, 0.f);

  int l = tid & 63, w = tid >> 6;
  int lr = l & 15, lq = l >> 4;
  v4f zero4 = {0.f, 0.f, 0.f, 0.f};
  v4f accP[4], accQ[4];
  #pragma unroll
  for (int j = 0; j < 4; ++j) { accP[j] = zero4; accQ[j] = zero4; }

  for (int ch = 0; ch < 7; ++ch) {
    __syncthreads();
    const float4* p4 = (const float4*)(p + ch*64*56);
    if (act) {
      int c4 = cg * 4;
      #pragma unroll
      for (int u = 0; u < 4; ++u) {
        int m = u*16 + rg;
        float4 v = p4[m*14 + cg];
        colsum.x += v.x; colsum.y += v.y; colsum.z += v.z; colsum.w += v.w;
        unsigned short h;
        h = f2bf(v.x); At[c4+0][m] = h; Alt[c4+0][m] = f2bf(v.x - bf2f(h));
        h = f2bf(v.y); At[c4+1][m] = h; Alt[c4+1][m] = f2bf(v.y - bf2f(h));
        h = f2bf(v.z); At[c4+2][m] = h; Alt[c4+2][m] = f2bf(v.z - bf2f(h));
        h = f2bf(v.w); At[c4+3][m] = h; Alt[c4+3][m] = f2bf(v.w - bf2f(h));
      }
    }
    __syncthreads();
    #pragma unroll
    for (int s2 = 0; s2 < 2; ++s2) {
      int kb = 32*s2 + 8*lq;
      v8s a = *(const v8s*)&At[16*w + lr][kb];
      #pragma unroll
      for (int j = 0; j < 4; ++j) {
        v8s bh = *(const v8s*)&At[16*j + lr][kb];
        v8s bl = *(const v8s*)&Alt[16*j + lr][kb];
        accP[j] = __builtin_amdgcn_mfma_f32_16x16x32_bf16(a, bh, accP[j], 0, 0, 0);
        accQ[j] = __builtin_amdgcn_mfma_f32_16x16x32_bf16(a, bl, accQ[j], 0, 0, 0);
      }
    }
  }

  __syncthreads();
  if (act) *(float4*)&red2[rg][cg*4] = colsum;
  __syncthreads();
  if (tid < 64) {
    float m = 0.f;
    if (tid < 56) {
      #pragma unroll
      for (int r = 0; r < 16; ++r) m += red2[r][tid];
    }
    muPart[((size_t)s*C_ + c)*64 + tid] = m;
  }
  __syncthreads();

  #pragma unroll
  for (int j = 0; j < 4; ++j) {
    #pragma unroll
    for (int e = 0; e < 4; ++e) {
      int r = 16*w + 4*lq + e, cc = 16*j + lr;
      Qbuf[r][cc] = accQ[j][e];
    }
  }
  __syncthreads();
  float* op = covPart + ((size_t)s*C_ + c)*DD_;
  #pragma unroll
  for (int j = 0; j < 4; ++j) {
    #pragma unroll
    for (int e = 0; e < 4; ++e) {
      int r = 16*w + 4*lq + e, cc = 16*j + lr;
      if (r < 56 && cc < 56) op[r*56 + cc] = accP[j][e] + accQ[j][e] + Qbuf[cc][r];
    }
  }
}

__global__ __launch_bounds__(256) void k_mured(const float* __restrict__ muPart, float* __restrict__ muT) {
  int idx = blockIdx.x*256 + threadIdx.x;
  if (idx >= C_*64) return;
  int c = idx >> 6, lane = idx & 63;
  float s = 0.f;
  for (int p = 0; p < 8; ++p) s += muPart[((size_t)p*C_ + c)*64 + lane];
  muT[idx] = s * (1.0f/M_);
}

__global__ __launch_bounds__(256) void k_finalize(const float* __restrict__ covPart, const float* __restrict__ muT,
                                                  const float* __restrict__ covIn, const float* __restrict__ muTrn,
                                                  const int* __restrict__ counter,
                                                  float* __restrict__ covTest, float* __restrict__ covTr) {
  int idx = blockIdx.x*256 + threadIdx.x;
  const int total = C_*DD_;
  if (idx < total) {
    int c = idx / DD_, r2 = idx % DD_, i = r2/56, j = r2%56;
    float ssum = 0.f;
    for (int s = 0; s < 8; ++s) ssum += covPart[((size_t)s*C_ + c)*DD_ + r2];
    float v = ssum*(1.0f/M_) - muT[c*64+i]*muT[c*64+j];
    if (i == j) v *= 1.001f;
    covTest[idx] = v;
  } else if (idx < 2*total) {
    int k = idx - total;
    int c = k / DD_, r2 = k % DD_, i = r2/56, j = r2%56;
    float cnt = (float)counter[0];
    covTr[k] = covIn[k]/cnt - muTrn[c*56+i]*muTrn[c*56+j];
  }
}

// Coupled Newton-Schulz via fp16-split MFMA.
__global__ __launch_bounds__(256) void k_ns(const float* __restrict__ covTr, const float* __restrict__ covTest,
                                            float* __restrict__ Sout, float* __restrict__ Zout) {
  __shared__ __align__(16) _Float16 mats[6][64][72];
  __shared__ float red[4];
  int tid = threadIdx.x;
  int which = blockIdx.x & 1, c = blockIdx.x >> 1;
  const float4* Ain4 = (const float4*)((which ? covTest : covTr) + (size_t)c * DD_);

  typedef _Float16 (*mat_t)[72];
  mat_t Yh = mats[0], Yl = mats[1], Zh = mats[2], Zl = mats[3], Th = mats[4], Tl = mats[5];

  float ss = 0.f;
  for (int i4 = tid; i4 < 784; i4 += 256) {
    float4 v = Ain4[i4];
    ss += v.x*v.x + v.y*v.y + v.z*v.z + v.w*v.w;
  }
  { unsigned* z = (unsigned*)mats; for (int i = tid; i < 13824; i += 256) z[i] = 0u; }
  #pragma unroll
  for (int off = 32; off > 0; off >>= 1) ss += __shfl_down(ss, off, 64);
  if ((tid & 63) == 0) red[tid >> 6] = ss;
  __syncthreads();
  float s = sqrtf(red[0] + red[1] + red[2] + red[3]);
  float inv = 1.f / s;

  for (int i4 = tid; i4 < 784; i4 += 256) {
    float4 v = Ain4[i4];
    int r = i4 / 14, cgx = (i4 % 14) * 4;
    float f0 = v.x*inv, f1 = v.y*inv, f2 = v.z*inv, f3 = v.w*inv;
    v4h hh, ll;
    hh.x = (_Float16)f0; ll.x = (_Float16)(f0 - (float)hh.x);
    hh.y = (_Float16)f1; ll.y = (_Float16)(f1 - (float)hh.y);
    hh.z = (_Float16)f2; ll.z = (_Float16)(f2 - (float)hh.z);
    hh.w = (_Float16)f3; ll.w = (_Float16)(f3 - (float)hh.w);
    *(v4h*)&Yh[r][cgx] = hh;
    *(v4h*)&Yl[r][cgx] = ll;
  }
  if (tid < 56) Zh[tid][tid] = (_Float16)1.0f;
  __syncthreads();

  int lane = tid & 63, w = tid >> 6, lr = lane & 15, lq = lane >> 4;
  v4f zero4 = {0.f, 0.f, 0.f, 0.f};
  float rs = sqrtf(s);
  float fac = which ? (1.f/rs) : rs;
  float* outp = (which ? Zout : Sout) + (size_t)c*DD_;

  for (int it = 0; it < NS_ITERS; ++it) {
    v4f accW[4] = {zero4, zero4, zero4, zero4};
    mm_split_h(Zh, Zl, Yh, Yl, w, lr, lq, accW);
    v4f Tv[4];
    #pragma unroll
    for (int jt = 0; jt < 4; ++jt) {
      #pragma unroll
      for (int e = 0; e < 4; ++e) {
        float dv = (16*w + 4*lq + e == 16*jt + lr) ? 1.5f : 0.f;
        Tv[jt][e] = dv - 0.5f*accW[jt][e];
      }
    }
    store_split_h(Th, Tl, w, lr, lq, Tv);
    __syncthreads();
    if (it == NS_ITERS - 1) {
      v4f accF[4] = {zero4, zero4, zero4, zero4};
      if (which == 0) mm_split_h(Yh, Yl, Th, Tl, w, lr, lq, accF);
      else            mm_split_h(Th, Tl, Zh, Zl, w, lr, lq, accF);
      #pragma unroll
      for (int jt = 0; jt < 4; ++jt) {
        #pragma unroll
        for (int e = 0; e < 4; ++e) {
          int i = 16*w + 4*lq + e, j = 16*jt + lr;
          if (i < 56 && j < 56) outp[i*56 + j] = accF[jt][e] * fac;
        }
      }
    } else {
      v4f accY[4] = {zero4, zero4, zero4, zero4};
      v4f accZ[4] = {zero4, zero4, zero4, zero4};
      mm_split_h(Yh, Yl, Th, Tl, w, lr, lq, accY);
      mm_split_h(Th, Tl, Zh, Zl, w, lr, lq, accZ);
      __syncthreads();
      store_split_h(Yh, Yl, w, lr, lq, accY);
      store_split_h(Zh, Zl, w, lr, lq, accZ);
      __syncthreads();
    }
  }
}

// Tm[c] = Zi[c] @ S[c]  via fp16-split MFMA
__global__ __launch_bounds__(256) void k_tmap(const float* __restrict__ Zi, const float* __restrict__ Sm,
                                              float* __restrict__ Tm) {
  __shared__ __align__(16) _Float16 mats[4][64][72];
  int c = blockIdx.x, tid = threadIdx.x;
  typedef _Float16 (*mat_t)[72];
  mat_t Ah = mats[0], Al = mats[1], Bh = mats[2], Bl = mats[3];
  { unsigned* z = (unsigned*)mats; for (int i = tid; i < 9216; i += 256) z[i] = 0u; }
  __syncthreads();
  const float4* Z4 = (const float4*)(Zi + (size_t)c*DD_);
  const float4* S4 = (const float4*)(Sm + (size_t)c*DD_);
  for (int i4 = tid; i4 < 784; i4 += 256) {
    int r = i4 / 14, cgx = (i4 % 14) * 4;
    float4 v = Z4[i4];
    v4h hh, ll;
    hh.x = (_Float16)v.x; ll.x = (_Float16)(v.x - (float)hh.x);
    hh.y = (_Float16)v.y; ll.y = (_Float16)(v.y - (float)hh.y);
    hh.z = (_Float16)v.z; ll.z = (_Float16)(v.z - (float)hh.z);
    hh.w = (_Float16)v.w; ll.w = (_Float16)(v.w - (float)hh.w);
    *(v4h*)&Ah[r][cgx] = hh;
    *(v4h*)&Al[r][cgx] = ll;
    v = S4[i4];
    hh.x = (_Float16)v.x; ll.x = (_Float16)(v.x - (float)hh.x);
    hh.y = (_Float16)v.y; ll.y = (_Float16)(v.y - (float)hh.y);
    hh.z = (_Float16)v.z; ll.z = (_Float16)(v.z - (float)hh.z);
    hh.w = (_Float16)v.w; ll.w = (_Float16)(v.w - (float)hh.w);
    *(v4h*)&Bh[r][cgx] = hh;
    *(v4h*)&Bl[r][cgx] = ll;
  }
  __syncthreads();
  int lane = tid & 63, w = tid >> 6, lr = lane & 15, lq = lane >> 4;
  v4f zero4 = {0.f, 0.f, 0.f, 0.f};
  v4f acc[4] = {zero4, zero4, zero4, zero4};
  mm_split_h(Ah, Al, Bh, Bl, w, lr, lq, acc);
  float* op = Tm + (size_t)c*DD_;
  #pragma unroll
  for (int jt = 0; jt < 4; ++jt) {
    #pragma unroll
    for (int e = 0; e < 4; ++e) {
      int i = 16*w + 4*lq + e, j = 16*jt + lr;
      if (i < 56 && j < 56) op[i*56 + j] = acc[jt][e];
    }
  }
}

// FUSED stage-1 apply + stage-2 stats.
// Block = (c, ngroup of 8). Per tile (c,n): Y = (X - muT)@T + muTrain (fp16 MFMA),
// write out[c][n][h][w] = Y[w][h]; accumulate stage-2 Gram (split-bf16 MFMA over
// At[w][h]=Y[w][h], K=h) and row-sums (mu2[w] = sum_h Y[w][h]).
__global__ __launch_bounds__(256) void k_apply1(const float* __restrict__ in, const float* __restrict__ muT,
                                                const float* __restrict__ Tmp, const float* __restrict__ muTrain,
                                                float* __restrict__ out,
                                                float* __restrict__ muPart, float* __restrict__ covPart) {
  int b = blockIdx.x;
  int c = b >> 3, ng = b & 7;
  __shared__ __align__(16) _Float16 Abf[64][72];
  __shared__ __align__(16) _Float16 Tt[64][72];
  __shared__ __align__(16) unsigned short At[64][72];
  __shared__ __align__(16) unsigned short Alt[64][72];
  __shared__ float Yb[56][57];
  __shared__ float smu[64], smt[64];
  __shared__ float redc[4][56];
  int tid = threadIdx.x;
  if (tid < 64) {
    smu[tid] = muT[c*64 + tid];
    smt[tid] = (tid < 56) ? muTrain[c*56 + tid] : 0.f;
  }
  { unsigned* z = (unsigned*)&Abf[0][0]; for (int i = tid; i < 2304; i += 256) z[i] = 0u; }
  { unsigned* z = (unsigned*)&Tt[0][0];  for (int i = tid; i < 2304; i += 256) z[i] = 0u; }
  { unsigned* z = (unsigned*)&At[0][0];  for (int i = tid; i < 2304; i += 256) z[i] = 0u; }
  { unsigned* z = (unsigned*)&Alt[0][0]; for (int i = tid; i < 2304; i += 256) z[i] = 0u; }
  __syncthreads();
  const float4* t4 = (const float4*)(Tmp + (size_t)c*DD_);
  for (int i = tid; i < 784; i += 256) {
    float4 t = t4[i];
    int row = i / 14, cgx = (i % 14) * 4;
    Tt[cgx+0][row] = (_Float16)t.x;
    Tt[cgx+1][row] = (_Float16)t.y;
    Tt[cgx+2][row] = (_Float16)t.z;
    Tt[cgx+3][row] = (_Float16)t.w;
  }
  int l = tid & 63, w = tid >> 6;
  int lr = l & 15, lq = l >> 4;
  v4f zero4 = {0.f, 0.f, 0.f, 0.f};
  v4f accP[4], accQ[4];
  #pragma unroll
  for (int j = 0; j < 4; ++j) { accP[j] = zero4; accQ[j] = zero4; }
  int w_ = tid >> 2, hg = tid & 3;       // colsum mapping (valid w_<56, tid<224)
  float colacc = 0.f;
  __syncthreads();

  for (int t = 0; t < 8; ++t) {
    int n = ng*8 + t;
    // ---- X tile -> centered fp16 ----
    const float4* p4 = (const float4*)(in + (size_t)c*PL_ + (size_t)n*3136);
    for (int i = tid; i < 784; i += 256) {
      float4 v = p4[i];
      int row = i / 14, cgx = (i % 14) * 4;
      v4h pk;
      pk.x = (_Float16)(v.x - smu[cgx+0]);
      pk.y = (_Float16)(v.y - smu[cgx+1]);
      pk.z = (_Float16)(v.z - smu[cgx+2]);
      pk.w = (_Float16)(v.w - smu[cgx+3]);
      *(v4h*)&Abf[row][cgx] = pk;
    }
    __syncthreads();
    // ---- apply MFMA ----
    v4f acc[4] = {zero4, zero4, zero4, zero4};
    #pragma unroll
    for (int s = 0; s < 2; ++s) {
      int kb = 32*s + 8*lq;
      v8h a = *(const v8h*)&Abf[16*w + lr][kb];
      #pragma unroll
      for (int j = 0; j < 4; ++j) {
        v8h bb = *(const v8h*)&Tt[16*j + lr][kb];
        acc[j] = __builtin_amdgcn_mfma_f32_16x16x32_f16(a, bb, acc[j], 0, 0, 0);
      }
    }
    // ---- epilogue: Yb[r=w][cc=h] = acc + muTrain[h] ----
    #pragma unroll
    for (int j = 0; j < 4; ++j) {
      #pragma unroll
      for (int e = 0; e < 4; ++e) {
        int r = 16*w + 4*lq + e, cc = 16*j + lr;
        if (r < 56 && cc < 56) Yb[r][cc] = acc[j][e] + smt[cc];
      }
    }
    __syncthreads();
    // ---- colsum (mu2[w] partial) ----
    if (tid < 224) {
      #pragma unroll
      for (int hh = 0; hh < 14; ++hh) colacc += Yb[w_][hg*14 + hh];
    }
    // ---- convert Yb -> split-bf16 At/Alt (direct copy: At[w][h]) ----
    for (int i = tid; i < 784; i += 256) {
      int r = i / 14, cgx = (i % 14) * 4;
      #pragma unroll
      for (int q = 0; q < 4; ++q) {
        float v = Yb[r][cgx+q];
        unsigned short h2 = f2bf(v);
        At[r][cgx+q] = h2;
        Alt[r][cgx+q] = f2bf(v - bf2f(h2));
      }
    }
    // ---- write out[c][n][h][w] = Yb[w][h] ----
    float4* op4 = (float4*)(out + (size_t)c*PL_ + (size_t)n*3136);
    for (int i4 = tid; i4 < 784; i4 += 256) {
      int h = i4 / 14, w4 = (i4 % 14) * 4;
      float4 o;
      o.x = Yb[w4+0][h]; o.y = Yb[w4+1][h]; o.z = Yb[w4+2][h]; o.w = Yb[w4+3][h];
      op4[i4] = o;
    }
    __syncthreads();
    // ---- stats MFMA: Gram over w-pairs, K = h (56 valid + zero pad) ----
    #pragma unroll
    for (int s2 = 0; s2 < 2; ++s2) {
      int kb = 32*s2 + 8*lq;
      v8s a = *(const v8s*)&At[16*w + lr][kb];
      #pragma unroll
      for (int j = 0; j < 4; ++j) {
        v8s bh = *(const v8s*)&At[16*j + lr][kb];
        v8s bl = *(const v8s*)&Alt[16*j + lr][kb];
        accP[j] = __builtin_amdgcn_mfma_f32_16x16x32_bf16(a, bh, accP[j], 0, 0, 0);
        accQ[j] = __builtin_amdgcn_mfma_f32_16x16x32_bf16(a, bl, accQ[j], 0, 0, 0);
      }
    }
  }

  // ---- emit muPart ----
  if (tid < 224) redc[hg][w_] = colacc;
  __syncthreads();
  if (tid < 64) {
    float m = 0.f;
    if (tid < 56) m = redc[0][tid] + redc[1][tid] + redc[2][tid] + redc[3][tid];
    muPart[((size_t)ng*C_ + c)*64 + tid] = m;
  }
  __syncthreads();
  // ---- emit covPart: S = P + Q + Q^T (stage Q into Yb) ----
  #pragma unroll
  for (int j = 0; j < 4; ++j) {
    #pragma unroll
    for (int e = 0; e < 4; ++e) {
      int r = 16*w + 4*lq + e, cc = 16*j + lr;
      if (r < 56 && cc < 56) Yb[r][cc] = accQ[j][e];
    }
  }
  __syncthreads();
  float* op = covPart + ((size_t)ng*C_ + c)*DD_;
  #pragma unroll
  for (int j = 0; j < 4; ++j) {
    #pragma unroll
    for (int e = 0; e < 4; ++e) {
      int r = 16*w + 4*lq + e, cc = 16*j + lr;
      if (r < 56 && cc < 56) op[r*56 + cc] = accP[j][e] + accQ[j][e] + Yb[cc][r];
    }
  }
}

// stage-2 apply: per-(c,n) tile Y = (X - muT)@T + muTrain, direct write (c,n,h,w)
__global__ __launch_bounds__(256) void k_apply2(const float* __restrict__ in, const float* __restrict__ muT,
                                                const float* __restrict__ Tmp, const float* __restrict__ muTrain,
                                                float* __restrict__ out) {
  int b = blockIdx.x;
  int c = b >> 6, n = b & 63;
  __shared__ __align__(16) char lds[18432];
  _Float16 (*Abf)[72] = (_Float16(*)[72])lds;
  _Float16 (*Tt)[72]  = (_Float16(*)[72])(lds + 9216);
  float (*Y)[67] = (float(*)[67])lds;
  __shared__ float smu[64], smt[64];
  int tid = threadIdx.x;
  if (tid < 64) {
    smu[tid] = muT[c*64 + tid];
    smt[tid] = (tid < 56) ? muTrain[c*56 + tid] : 0.f;
  }
  if (tid < 128) {
    int row = tid & 63;
    _Float16 (*Mz)[72] = (tid < 64) ? Abf : Tt;
    *(float4*)&Mz[row][56] = make_float4(0.f, 0.f, 0.f, 0.f);
  }
  __syncthreads();
  const float4* p4 = (const float4*)(in + (size_t)c*PL_ + (size_t)n*3136);
  const float4* t4 = (const float4*)(Tmp + (size_t)c*DD_);
  for (int i = tid; i < 784; i += 256) {
    float4 v = p4[i];
    int row = i / 14, cgx = (i % 14) * 4;
    v4h pk;
    pk.x = (_Float16)(v.x - smu[cgx+0]);
    pk.y = (_Float16)(v.y - smu[cgx+1]);
    pk.z = (_Float16)(v.z - smu[cgx+2]);
    pk.w = (_Float16)(v.w - smu[cgx+3]);
    *(v4h*)&Abf[row][cgx] = pk;
    float4 t = t4[i];
    Tt[cgx+0][row] = (_Float16)t.x;
    Tt[cgx+1][row] = (_Float16)t.y;
    Tt[cgx+2][row] = (_Float16)t.z;
    Tt[cgx+3][row] = (_Float16)t.w;
  }
  __syncthreads();
  int l = tid & 63, w = tid >> 6;
  int lr = l & 15, lq = l >> 4;
  v4f zero4 = {0.f, 0.f, 0.f, 0.f};
  v4f acc[4];
  #pragma unroll
  for (int j = 0; j < 4; ++j) acc[j] = zero4;
  #pragma unroll
  for (int s = 0; s < 2; ++s) {
    int kb = 32*s + 8*lq;
    v8h a = *(const v8h*)&Abf[16*w + lr][kb];
    #pragma unroll
    for (int j = 0; j < 4; ++j) {
      v8h bb = *(const v8h*)&Tt[16*j + lr][kb];
      acc[j] = __builtin_amdgcn_mfma_f32_16x16x32_f16(a, bb, acc[j], 0, 0, 0);
    }
  }
  __syncthreads();
  #pragma unroll
  for (int j = 0; j < 4; ++j) {
    #pragma unroll
    for (int e = 0; e < 4; ++e) {
      int r = 16*w + 4*lq + e, cc = 16*j + lr;
      Y[r][cc] = acc[j][e] + smt[cc];
    }
  }
  __syncthreads();
  float4* op4 = (float4*)(out + (size_t)c*PL_ + (size_t)n*3136);
  for (int i4 = tid; i4 < 784; i4 += 256) {
    int h = i4 / 14, w4 = (i4 % 14) * 4;
    float4 o;
    o.x = Y[h][w4+0]; o.y = Y[h][w4+1]; o.z = Y[h][w4+2]; o.w = Y[h][w4+3];
    op4[i4] = o;
  }
}

// A2 (c, n, h, w) -> out (n, h, w, c)  — pipelined, TG tiles/block
__global__ __launch_bounds__(256) void k_tout(const float* __restrict__ A2, float* __restrict__ out) {
  int b = blockIdx.x;
  int cchunk = b & 3, g = b >> 2;
  int c0 = cchunk * 64;
  __shared__ float t[64][57];
  int tid = threadIdx.x;
  float4 regs[4], nxt[4];
  {
    int nh = g*TG;
    const float* Ap = A2 + (size_t)c0*PL_ + (size_t)nh*56;
    #pragma unroll
    for (int it = 0; it < 4; ++it) {
      int i4 = tid + 256*it;
      if (i4 < 896) { int cc = i4/14, wg = (i4%14)*4; regs[it] = *(const float4*)&Ap[(size_t)cc*PL_ + wg]; }
    }
  }
  for (int tt = 0; tt < TG; ++tt) {
    int nh = g*TG + tt;
    if (tt+1 < TG) {
      const float* Aq = A2 + (size_t)c0*PL_ + (size_t)(nh+1)*56;
      #pragma unroll
      for (int it = 0; it < 4; ++it) {
        int i4 = tid + 256*it;
        if (i4 < 896) { int cc = i4/14, wg = (i4%14)*4; nxt[it] = *(const float4*)&Aq[(size_t)cc*PL_ + wg]; }
      }
    }
    #pragma unroll
    for (int it = 0; it < 4; ++it) {
      int i4 = tid + 256*it;
      if (i4 < 896) {
        int cc = i4/14, wg = (i4%14)*4;
        t[cc][wg+0] = regs[it].x; t[cc][wg+1] = regs[it].y;
        t[cc][wg+2] = regs[it].z; t[cc][wg+3] = regs[it].w;
      }
    }
    __syncthreads();
    float4* op4 = (float4*)(out + (size_t)nh*56*256 + c0);
    #pragma unroll
    for (int it = 0; it < 4; ++it) {
      int i4 = tid + 256*it;
      if (i4 < 896) {
        int w = i4 >> 4, cg = i4 & 15;
        float4 o;
        o.x = t[4*cg+0][w]; o.y = t[4*cg+1][w]; o.z = t[4*cg+2][w]; o.w = t[4*cg+3][w];
        op4[(size_t)w*64 + cg] = o;
      }
    }
    __syncthreads();
    #pragma unroll
    for (int it = 0; it < 4; ++it) regs[it] = nxt[it];
  }
}

extern "C" void kernel_launch(void* const* d_in, const int* in_sizes, int n_in,
                              void* d_out, int out_size, void* d_ws, size_t ws_size,
                              hipStream_t stream) {
  (void)in_sizes; (void)n_in; (void)out_size;
  const float* x    = (const float*)d_in[0];
  const float* covH = (const float*)d_in[1];
  const float* muH  = (const float*)d_in[2];
  const float* covW = (const float*)d_in[3];
  const float* muW  = (const float*)d_in[4];
  const int*   cnt  = (const int*)d_in[5];
  float* out = (float*)d_out;

  char* ws = (char*)d_ws;
  size_t off = 0;
  auto alloc = [&](size_t nfloats) {
    float* p = (float*)(ws + off);
    off += ((nfloats*sizeof(float) + 255) / 256) * 256;
    return p;
  };
  float* A       = alloc((size_t)C_ * PL_);
  float* covPart = alloc((size_t)8 * C_ * DD_);
  float* muPart  = alloc((size_t)8 * C_ * 64);
  float* covTest = alloc((size_t)C_ * DD_);
  float* covTr   = alloc((size_t)C_ * DD_);
  float* Sm      = alloc((size_t)C_ * DD_);
  float* Zim     = alloc((size_t)C_ * DD_);
  float* Tm      = alloc((size_t)C_ * DD_);
  float* muT     = alloc((size_t)C_ * 64);
  if (off > ws_size) return;

  dim3 blk(256);
  const int finGrid = (2*C_*DD_ + 255)/256;

  k_tin<<<dim3(4 * (M_/TG)), blk, 0, stream>>>(x, A);

  // ---- stage 1 (H axis) ----
  k_stats   <<<dim3(2048),  blk, 0, stream>>>(A, muPart, covPart);
  k_mured   <<<dim3(64),    blk, 0, stream>>>(muPart, muT);
  k_finalize<<<dim3(finGrid), blk, 0, stream>>>(covPart, muT, covH, muH, cnt, covTest, covTr);
  k_ns      <<<dim3(512),   blk, 0, stream>>>(covTr, covTest, Sm, Zim);
  k_tmap    <<<dim3(256),   blk, 0, stream>>>(Zim, Sm, Tm);
  // fused stage-1 apply + stage-2 stats
  k_apply1  <<<dim3(2048),  blk, 0, stream>>>(A, muT, Tm, muH, out, muPart, covPart);

  // ---- stage 2 (W axis) ----
  k_mured   <<<dim3(64),    blk, 0, stream>>>(muPart, muT);
  k_finalize<<<dim3(finGrid), blk, 0, stream>>>(covPart, muT, covW, muW, cnt, covTest, covTr);
  k_ns      <<<dim3(512),   blk, 0, stream>>>(covTr, covTest, Sm, Zim);
  k_tmap    <<<dim3(256),   blk, 0, stream>>>(Zim, Sm, Tm);
  k_apply2  <<<dim3(16384), blk, 0, stream>>>(out, muT, Tm, muW, A);

  k_tout<<<dim3(4 * (M_/TG)), blk, 0, stream>>>(A, out);
}

// Round 7
// 579.547 us; speedup vs baseline: 1.1327x; 1.1327x over previous
//
#include <hip/hip_runtime.h>

#define C_ 256
#define D_ 56
#define N_ 64
#define M_ 3584     // rows per channel (N*56), same both stages since H==W
#define DD_ 3136    // 56*56
#define PL_ 200704  // per-channel plane = M_*56
#define PL4_ 50176  // PL_/4
#define NS_ITERS 16

typedef __attribute__((ext_vector_type(8))) short v8s;
typedef __attribute__((ext_vector_type(8))) _Float16 v8h;
typedef __attribute__((ext_vector_type(4))) _Float16 v4h;
typedef __attribute__((ext_vector_type(4))) float v4f;

__device__ __forceinline__ unsigned short f2bf(float f) {
  union { float f; unsigned u; } x; x.f = f;
  unsigned r = x.u + 0x7FFFu + ((x.u >> 16) & 1u);
  return (unsigned short)(r >> 16);
}
__device__ __forceinline__ float bf2f(unsigned short h) {
  union { unsigned u; float f; } x; x.u = ((unsigned)h) << 16;
  return x.f;
}

// x (N,H,W,C) -> A (C, n*56+w, h)
// Block = (cchunk of 64 channels, group of 4 consecutive m=(n,w)). 56%4==0 so the
// 4 m's share one n. Writes per channel: 4 rows x 224B = 896B contiguous (DRAM-
// page friendly); reads per (mloc,h): 64 channels = 256B, 4 w's -> 1KB locality.
__global__ __launch_bounds__(256) void k_tin(const float* __restrict__ x, float* __restrict__ A) {
  int b = blockIdx.x;
  int cchunk = b & 3, g = b >> 2;
  int c0 = cchunk * 64;
  int m0 = g * 4;
  int n = m0 / 56, w0 = m0 % 56;
  __shared__ float t[4][56][65];   // [mloc][h][cc]  58240 B
  int tid = threadIdx.x;
  const float4* x4 = (const float4*)x;
  // read: i -> (mloc, h, cg)
  #pragma unroll
  for (int it = 0; it < 14; ++it) {
    int i = tid + 256*it;
    int mloc = i / 896, r = i % 896;
    int h = r >> 4, cg = r & 15;
    float4 v = x4[((size_t)n*3136 + (size_t)h*56 + (w0+mloc))*64 + (c0>>2) + cg];
    *(float4*)&t[mloc][h][4*cg] = v;
  }
  __syncthreads();
  // write: j -> (cc, mloc, hg)
  float4* A4 = (float4*)A;
  #pragma unroll
  for (int it = 0; it < 14; ++it) {
    int j = tid + 256*it;
    int q = j / 14, hg = j % 14;
    int cc = q >> 2, mloc = q & 3;
    float4 o;
    o.x = t[mloc][4*hg+0][cc];
    o.y = t[mloc][4*hg+1][cc];
    o.z = t[mloc][4*hg+2][cc];
    o.w = t[mloc][4*hg+3][cc];
    A4[(size_t)(c0+cc)*PL4_ + (size_t)(m0+mloc)*14 + hg] = o;
  }
}

// ---------- fp16-split MFMA helpers ----------
__device__ __forceinline__ void mm_split_h(const _Float16 (*Ah)[72], const _Float16 (*Al)[72],
                                           const _Float16 (*Bh)[72], const _Float16 (*Bl)[72],
                                           int w, int lr, int lq, v4f (&acc)[4]) {
  v8h ah[2], al[2], bh[4][2], bl[4][2];
  #pragma unroll
  for (int s = 0; s < 2; ++s) {
    int kb = 32*s + 8*lq;
    ah[s] = *(const v8h*)&Ah[16*w + lr][kb];
    al[s] = *(const v8h*)&Al[16*w + lr][kb];
    #pragma unroll
    for (int jt = 0; jt < 4; ++jt) {
      bh[jt][s] = *(const v8h*)&Bh[16*jt + lr][kb];
      bl[jt][s] = *(const v8h*)&Bl[16*jt + lr][kb];
    }
  }
  #pragma unroll
  for (int jt = 0; jt < 4; ++jt) {
    #pragma unroll
    for (int s = 0; s < 2; ++s) {
      acc[jt] = __builtin_amdgcn_mfma_f32_16x16x32_f16(ah[s], bh[jt][s], acc[jt], 0, 0, 0);
      acc[jt] = __builtin_amdgcn_mfma_f32_16x16x32_f16(ah[s], bl[jt][s], acc[jt], 0, 0, 0);
      acc[jt] = __builtin_amdgcn_mfma_f32_16x16x32_f16(al[s], bh[jt][s], acc[jt], 0, 0, 0);
    }
  }
}

__device__ __forceinline__ void store_split_h(_Float16 (*H)[72], _Float16 (*L)[72],
                                              int w, int lr, int lq, const v4f (&val)[4]) {
  #pragma unroll
  for (int jt = 0; jt < 4; ++jt) {
    #pragma unroll
    for (int e = 0; e < 4; ++e) {
      int i = 16*w + 4*lq + e, j = 16*jt + lr;
      float v = val[jt][e];
      _Float16 h = (_Float16)v;
      H[i][j] = h;
      L[i][j] = (_Float16)(v - (float)h);
    }
  }
}

// Fused: raw column-sum (fp32 exact, in-register) + raw second moment via split-bf16 MFMA.
__global__ __launch_bounds__(256) void k_stats(const float* __restrict__ in,
                                               float* __restrict__ muPart,
                                               float* __restrict__ covPart) {
  int b = blockIdx.x;
  int c = b >> 3, s = b & 7;
  const float* p = in + (size_t)c*PL_ + (size_t)(s*448)*56;
  __shared__ __align__(16) char lds[18432];
  unsigned short (*At)[72]  = (unsigned short(*)[72])lds;
  unsigned short (*Alt)[72] = (unsigned short(*)[72])(lds + 9216);
  float (*Qbuf)[66] = (float(*)[66])lds;
  float (*red2)[60] = (float(*)[60])lds;
  int tid = threadIdx.x;
  int cg = tid % 14, rg = tid / 14;
  bool act = tid < 224;
  float4 colsum = make_float4(0.f, 0.f, 0.f, 0.f);

  int l = tid & 63, w = tid >> 6;
  int lr = l & 15, lq = l >> 4;
  v4f zero4 = {0.f, 0.f, 0.f, 0.f};
  v4f accP[4], accQ[4];
  #pragma unroll
  for (int j = 0; j < 4; ++j) { accP[j] = zero4; accQ[j] = zero4; }

  for (int ch = 0; ch < 7; ++ch) {
    __syncthreads();
    const float4* p4 = (const float4*)(p + ch*64*56);
    if (act) {
      int c4 = cg * 4;
      #pragma unroll
      for (int u = 0; u < 4; ++u) {
        int m = u*16 + rg;
        float4 v = p4[m*14 + cg];
        colsum.x += v.x; colsum.y += v.y; colsum.z += v.z; colsum.w += v.w;
        unsigned short h;
        h = f2bf(v.x); At[c4+0][m] = h; Alt[c4+0][m] = f2bf(v.x - bf2f(h));
        h = f2bf(v.y); At[c4+1][m] = h; Alt[c4+1][m] = f2bf(v.y - bf2f(h));
        h = f2bf(v.z); At[c4+2][m] = h; Alt[c4+2][m] = f2bf(v.z - bf2f(h));
        h = f2bf(v.w); At[c4+3][m] = h; Alt[c4+3][m] = f2bf(v.w - bf2f(h));
      }
    }
    __syncthreads();
    #pragma unroll
    for (int s2 = 0; s2 < 2; ++s2) {
      int kb = 32*s2 + 8*lq;
      v8s a = *(const v8s*)&At[16*w + lr][kb];
      #pragma unroll
      for (int j = 0; j < 4; ++j) {
        v8s bh = *(const v8s*)&At[16*j + lr][kb];
        v8s bl = *(const v8s*)&Alt[16*j + lr][kb];
        accP[j] = __builtin_amdgcn_mfma_f32_16x16x32_bf16(a, bh, accP[j], 0, 0, 0);
        accQ[j] = __builtin_amdgcn_mfma_f32_16x16x32_bf16(a, bl, accQ[j], 0, 0, 0);
      }
    }
  }

  __syncthreads();
  if (act) *(float4*)&red2[rg][cg*4] = colsum;
  __syncthreads();
  if (tid < 64) {
    float m = 0.f;
    if (tid < 56) {
      #pragma unroll
      for (int r = 0; r < 16; ++r) m += red2[r][tid];
    }
    muPart[((size_t)s*C_ + c)*64 + tid] = m;
  }
  __syncthreads();

  #pragma unroll
  for (int j = 0; j < 4; ++j) {
    #pragma unroll
    for (int e = 0; e < 4; ++e) {
      int r = 16*w + 4*lq + e, cc = 16*j + lr;
      Qbuf[r][cc] = accQ[j][e];
    }
  }
  __syncthreads();
  float* op = covPart + ((size_t)s*C_ + c)*DD_;
  #pragma unroll
  for (int j = 0; j < 4; ++j) {
    #pragma unroll
    for (int e = 0; e < 4; ++e) {
      int r = 16*w + 4*lq + e, cc = 16*j + lr;
      if (r < 56 && cc < 56) op[r*56 + cc] = accP[j][e] + accQ[j][e] + Qbuf[cc][r];
    }
  }
}

__global__ __launch_bounds__(256) void k_mured(const float* __restrict__ muPart, float* __restrict__ muT) {
  int idx = blockIdx.x*256 + threadIdx.x;
  if (idx >= C_*64) return;
  int c = idx >> 6, lane = idx & 63;
  float s = 0.f;
  for (int p = 0; p < 8; ++p) s += muPart[((size_t)p*C_ + c)*64 + lane];
  muT[idx] = s * (1.0f/M_);
}

__global__ __launch_bounds__(256) void k_finalize(const float* __restrict__ covPart, const float* __restrict__ muT,
                                                  const float* __restrict__ covIn, const float* __restrict__ muTrn,
                                                  const int* __restrict__ counter,
                                                  float* __restrict__ covTest, float* __restrict__ covTr) {
  int idx = blockIdx.x*256 + threadIdx.x;
  const int total = C_*DD_;
  if (idx < total) {
    int c = idx / DD_, r2 = idx % DD_, i = r2/56, j = r2%56;
    float ssum = 0.f;
    for (int s = 0; s < 8; ++s) ssum += covPart[((size_t)s*C_ + c)*DD_ + r2];
    float v = ssum*(1.0f/M_) - muT[c*64+i]*muT[c*64+j];
    if (i == j) v *= 1.001f;
    covTest[idx] = v;
  } else if (idx < 2*total) {
    int k = idx - total;
    int c = k / DD_, r2 = k % DD_, i = r2/56, j = r2%56;
    float cnt = (float)counter[0];
    covTr[k] = covIn[k]/cnt - muTrn[c*56+i]*muTrn[c*56+j];
  }
}

// Coupled Newton-Schulz via fp16-split MFMA.
__global__ __launch_bounds__(256) void k_ns(const float* __restrict__ covTr, const float* __restrict__ covTest,
                                            float* __restrict__ Sout, float* __restrict__ Zout) {
  __shared__ __align__(16) _Float16 mats[6][64][72];
  __shared__ float red[4];
  int tid = threadIdx.x;
  int which = blockIdx.x & 1, c = blockIdx.x >> 1;
  const float4* Ain4 = (const float4*)((which ? covTest : covTr) + (size_t)c * DD_);

  typedef _Float16 (*mat_t)[72];
  mat_t Yh = mats[0], Yl = mats[1], Zh = mats[2], Zl = mats[3], Th = mats[4], Tl = mats[5];

  float ss = 0.f;
  for (int i4 = tid; i4 < 784; i4 += 256) {
    float4 v = Ain4[i4];
    ss += v.x*v.x + v.y*v.y + v.z*v.z + v.w*v.w;
  }
  { unsigned* z = (unsigned*)mats; for (int i = tid; i < 13824; i += 256) z[i] = 0u; }
  #pragma unroll
  for (int off = 32; off > 0; off >>= 1) ss += __shfl_down(ss, off, 64);
  if ((tid & 63) == 0) red[tid >> 6] = ss;
  __syncthreads();
  float s = sqrtf(red[0] + red[1] + red[2] + red[3]);
  float inv = 1.f / s;

  for (int i4 = tid; i4 < 784; i4 += 256) {
    float4 v = Ain4[i4];
    int r = i4 / 14, cgx = (i4 % 14) * 4;
    float f0 = v.x*inv, f1 = v.y*inv, f2 = v.z*inv, f3 = v.w*inv;
    v4h hh, ll;
    hh.x = (_Float16)f0; ll.x = (_Float16)(f0 - (float)hh.x);
    hh.y = (_Float16)f1; ll.y = (_Float16)(f1 - (float)hh.y);
    hh.z = (_Float16)f2; ll.z = (_Float16)(f2 - (float)hh.z);
    hh.w = (_Float16)f3; ll.w = (_Float16)(f3 - (float)hh.w);
    *(v4h*)&Yh[r][cgx] = hh;
    *(v4h*)&Yl[r][cgx] = ll;
  }
  if (tid < 56) Zh[tid][tid] = (_Float16)1.0f;
  __syncthreads();

  int lane = tid & 63, w = tid >> 6, lr = lane & 15, lq = lane >> 4;
  v4f zero4 = {0.f, 0.f, 0.f, 0.f};
  float rs = sqrtf(s);
  float fac = which ? (1.f/rs) : rs;
  float* outp = (which ? Zout : Sout) + (size_t)c*DD_;

  for (int it = 0; it < NS_ITERS; ++it) {
    v4f accW[4] = {zero4, zero4, zero4, zero4};
    mm_split_h(Zh, Zl, Yh, Yl, w, lr, lq, accW);
    v4f Tv[4];
    #pragma unroll
    for (int jt = 0; jt < 4; ++jt) {
      #pragma unroll
      for (int e = 0; e < 4; ++e) {
        float dv = (16*w + 4*lq + e == 16*jt + lr) ? 1.5f : 0.f;
        Tv[jt][e] = dv - 0.5f*accW[jt][e];
      }
    }
    store_split_h(Th, Tl, w, lr, lq, Tv);
    __syncthreads();
    if (it == NS_ITERS - 1) {
      v4f accF[4] = {zero4, zero4, zero4, zero4};
      if (which == 0) mm_split_h(Yh, Yl, Th, Tl, w, lr, lq, accF);
      else            mm_split_h(Th, Tl, Zh, Zl, w, lr, lq, accF);
      #pragma unroll
      for (int jt = 0; jt < 4; ++jt) {
        #pragma unroll
        for (int e = 0; e < 4; ++e) {
          int i = 16*w + 4*lq + e, j = 16*jt + lr;
          if (i < 56 && j < 56) outp[i*56 + j] = accF[jt][e] * fac;
        }
      }
    } else {
      v4f accY[4] = {zero4, zero4, zero4, zero4};
      v4f accZ[4] = {zero4, zero4, zero4, zero4};
      mm_split_h(Yh, Yl, Th, Tl, w, lr, lq, accY);
      mm_split_h(Th, Tl, Zh, Zl, w, lr, lq, accZ);
      __syncthreads();
      store_split_h(Yh, Yl, w, lr, lq, accY);
      store_split_h(Zh, Zl, w, lr, lq, accZ);
      __syncthreads();
    }
  }
}

// Tm[c] = Zi[c] @ S[c]  via fp16-split MFMA
__global__ __launch_bounds__(256) void k_tmap(const float* __restrict__ Zi, const float* __restrict__ Sm,
                                              float* __restrict__ Tm) {
  __shared__ __align__(16) _Float16 mats[4][64][72];
  int c = blockIdx.x, tid = threadIdx.x;
  typedef _Float16 (*mat_t)[72];
  mat_t Ah = mats[0], Al = mats[1], Bh = mats[2], Bl = mats[3];
  { unsigned* z = (unsigned*)mats; for (int i = tid; i < 9216; i += 256) z[i] = 0u; }
  __syncthreads();
  const float4* Z4 = (const float4*)(Zi + (size_t)c*DD_);
  const float4* S4 = (const float4*)(Sm + (size_t)c*DD_);
  for (int i4 = tid; i4 < 784; i4 += 256) {
    int r = i4 / 14, cgx = (i4 % 14) * 4;
    float4 v = Z4[i4];
    v4h hh, ll;
    hh.x = (_Float16)v.x; ll.x = (_Float16)(v.x - (float)hh.x);
    hh.y = (_Float16)v.y; ll.y = (_Float16)(v.y - (float)hh.y);
    hh.z = (_Float16)v.z; ll.z = (_Float16)(v.z - (float)hh.z);
    hh.w = (_Float16)v.w; ll.w = (_Float16)(v.w - (float)hh.w);
    *(v4h*)&Ah[r][cgx] = hh;
    *(v4h*)&Al[r][cgx] = ll;
    v = S4[i4];
    hh.x = (_Float16)v.x; ll.x = (_Float16)(v.x - (float)hh.x);
    hh.y = (_Float16)v.y; ll.y = (_Float16)(v.y - (float)hh.y);
    hh.z = (_Float16)v.z; ll.z = (_Float16)(v.z - (float)hh.z);
    hh.w = (_Float16)v.w; ll.w = (_Float16)(v.w - (float)hh.w);
    *(v4h*)&Bh[r][cgx] = hh;
    *(v4h*)&Bl[r][cgx] = ll;
  }
  __syncthreads();
  int lane = tid & 63, w = tid >> 6, lr = lane & 15, lq = lane >> 4;
  v4f zero4 = {0.f, 0.f, 0.f, 0.f};
  v4f acc[4] = {zero4, zero4, zero4, zero4};
  mm_split_h(Ah, Al, Bh, Bl, w, lr, lq, acc);
  float* op = Tm + (size_t)c*DD_;
  #pragma unroll
  for (int jt = 0; jt < 4; ++jt) {
    #pragma unroll
    for (int e = 0; e < 4; ++e) {
      int i = 16*w + 4*lq + e, j = 16*jt + lr;
      if (i < 56 && j < 56) op[i*56 + j] = acc[jt][e];
    }
  }
}

// Per-(c,n) 56x56 tile: Y = (X - muT) @ T + muTrain via fp16 MFMA, fp32 accum.
__global__ __launch_bounds__(256) void k_apply(const float* __restrict__ in, const float* __restrict__ muT,
                                               const float* __restrict__ Tmp, const float* __restrict__ muTrain,
                                               float* __restrict__ out, int stage) {
  int b = blockIdx.x;
  int c = b >> 6, n = b & 63;
  __shared__ __align__(16) char lds[18432];
  _Float16 (*Abf)[72] = (_Float16(*)[72])lds;
  _Float16 (*Tt)[72]  = (_Float16(*)[72])(lds + 9216);
  float (*Y)[67] = (float(*)[67])lds;
  __shared__ float smu[64], smt[64];
  int tid = threadIdx.x;
  if (tid < 64) {
    smu[tid] = muT[c*64 + tid];
    smt[tid] = (tid < 56) ? muTrain[c*56 + tid] : 0.f;
  }
  if (tid < 128) {
    int row = tid & 63;
    _Float16 (*Mz)[72] = (tid < 64) ? Abf : Tt;
    *(float4*)&Mz[row][56] = make_float4(0.f, 0.f, 0.f, 0.f);
  }
  __syncthreads();
  const float4* p4 = (const float4*)(in + (size_t)c*PL_ + (size_t)n*3136);
  const float4* t4 = (const float4*)(Tmp + (size_t)c*DD_);
  for (int i = tid; i < 784; i += 256) {
    float4 v = p4[i];
    int row = i / 14, cgx = (i % 14) * 4;
    v4h pk;
    pk.x = (_Float16)(v.x - smu[cgx+0]);
    pk.y = (_Float16)(v.y - smu[cgx+1]);
    pk.z = (_Float16)(v.z - smu[cgx+2]);
    pk.w = (_Float16)(v.w - smu[cgx+3]);
    *(v4h*)&Abf[row][cgx] = pk;
    float4 t = t4[i];
    Tt[cgx+0][row] = (_Float16)t.x;
    Tt[cgx+1][row] = (_Float16)t.y;
    Tt[cgx+2][row] = (_Float16)t.z;
    Tt[cgx+3][row] = (_Float16)t.w;
  }
  __syncthreads();
  int l = tid & 63, w = tid >> 6;
  int lr = l & 15, lq = l >> 4;
  v4f zero4 = {0.f, 0.f, 0.f, 0.f};
  v4f acc[4];
  #pragma unroll
  for (int j = 0; j < 4; ++j) acc[j] = zero4;
  #pragma unroll
  for (int s = 0; s < 2; ++s) {
    int kb = 32*s + 8*lq;
    v8h a = *(const v8h*)&Abf[16*w + lr][kb];
    #pragma unroll
    for (int j = 0; j < 4; ++j) {
      v8h bb = *(const v8h*)&Tt[16*j + lr][kb];
      acc[j] = __builtin_amdgcn_mfma_f32_16x16x32_f16(a, bb, acc[j], 0, 0, 0);
    }
  }
  __syncthreads();
  #pragma unroll
  for (int j = 0; j < 4; ++j) {
    #pragma unroll
    for (int e = 0; e < 4; ++e) {
      int r = 16*w + 4*lq + e, cc = 16*j + lr;
      Y[r][cc] = acc[j][e] + smt[cc];
    }
  }
  __syncthreads();
  float4* op4 = (float4*)(out + (size_t)c*PL_ + (size_t)n*3136);
  if (stage == 1) {
    for (int i4 = tid; i4 < 784; i4 += 256) {
      int h = i4 / 14, w4 = (i4 % 14) * 4;
      float4 o;
      o.x = Y[w4+0][h]; o.y = Y[w4+1][h]; o.z = Y[w4+2][h]; o.w = Y[w4+3][h];
      op4[i4] = o;
    }
  } else {
    for (int i4 = tid; i4 < 784; i4 += 256) {
      int h = i4 / 14, w4 = (i4 % 14) * 4;
      float4 o;
      o.x = Y[h][w4+0]; o.y = Y[h][w4+1]; o.z = Y[h][w4+2]; o.w = Y[h][w4+3];
      op4[i4] = o;
    }
  }
}

// A2 (c, n, h, w) -> out (n, h, w, c)
// Block = (cchunk of 64, group of 4 consecutive nh). Reads per channel 896B
// contiguous; writes 256B segments dense within the 4 x 57KB output region.
__global__ __launch_bounds__(256) void k_tout(const float* __restrict__ A2, float* __restrict__ out) {
  int b = blockIdx.x;
  int cchunk = b & 3, g = b >> 2;
  int c0 = cchunk * 64;
  int nh0 = g * 4;
  __shared__ float t[4][56][65];   // [mloc][w][cc]
  int tid = threadIdx.x;
  const float4* A4 = (const float4*)A2;
  // read: j -> (cc, mloc, wg)
  #pragma unroll
  for (int it = 0; it < 14; ++it) {
    int j = tid + 256*it;
    int q = j / 14, wg = j % 14;
    int cc = q >> 2, mloc = q & 3;
    float4 v = A4[(size_t)(c0+cc)*PL4_ + (size_t)(nh0+mloc)*14 + wg];
    t[mloc][4*wg+0][cc] = v.x;
    t[mloc][4*wg+1][cc] = v.y;
    t[mloc][4*wg+2][cc] = v.z;
    t[mloc][4*wg+3][cc] = v.w;
  }
  __syncthreads();
  // write: i -> (mloc, w, cg)
  float4* o4 = (float4*)out;
  #pragma unroll
  for (int it = 0; it < 14; ++it) {
    int i = tid + 256*it;
    int mloc = i / 896, r = i % 896;
    int w = r >> 4, cg = r & 15;
    float4 o;
    o.x = t[mloc][w][4*cg+0];
    o.y = t[mloc][w][4*cg+1];
    o.z = t[mloc][w][4*cg+2];
    o.w = t[mloc][w][4*cg+3];
    o4[((size_t)(nh0+mloc)*56 + w)*64 + (c0>>2) + cg] = o;
  }
}

extern "C" void kernel_launch(void* const* d_in, const int* in_sizes, int n_in,
                              void* d_out, int out_size, void* d_ws, size_t ws_size,
                              hipStream_t stream) {
  (void)in_sizes; (void)n_in; (void)out_size;
  const float* x    = (const float*)d_in[0];
  const float* covH = (const float*)d_in[1];
  const float* muH  = (const float*)d_in[2];
  const float* covW = (const float*)d_in[3];
  const float* muW  = (const float*)d_in[4];
  const int*   cnt  = (const int*)d_in[5];
  float* out = (float*)d_out;

  char* ws = (char*)d_ws;
  size_t off = 0;
  auto alloc = [&](size_t nfloats) {
    float* p = (float*)(ws + off);
    off += ((nfloats*sizeof(float) + 255) / 256) * 256;
    return p;
  };
  float* A       = alloc((size_t)C_ * PL_);
  float* covPart = alloc((size_t)8 * C_ * DD_);
  float* muPart  = alloc((size_t)8 * C_ * 64);
  float* covTest = alloc((size_t)C_ * DD_);
  float* covTr   = alloc((size_t)C_ * DD_);
  float* Sm      = alloc((size_t)C_ * DD_);
  float* Zim     = alloc((size_t)C_ * DD_);
  float* Tm      = alloc((size_t)C_ * DD_);
  float* muT     = alloc((size_t)C_ * 64);
  if (off > ws_size) return;

  dim3 blk(256);
  const int finGrid = (2*C_*DD_ + 255)/256;

  k_tin<<<dim3(4 * (M_/4)), blk, 0, stream>>>(x, A);

  // ---- stage 1 (H axis) ----
  k_stats   <<<dim3(2048),  blk, 0, stream>>>(A, muPart, covPart);
  k_mured   <<<dim3(64),    blk, 0, stream>>>(muPart, muT);
  k_finalize<<<dim3(finGrid), blk, 0, stream>>>(covPart, muT, covH, muH, cnt, covTest, covTr);
  k_ns      <<<dim3(512),   blk, 0, stream>>>(covTr, covTest, Sm, Zim);
  k_tmap    <<<dim3(256),   blk, 0, stream>>>(Zim, Sm, Tm);
  k_apply   <<<dim3(16384), blk, 0, stream>>>(A, muT, Tm, muH, out, 1);

  // ---- stage 2 (W axis) ----
  k_stats   <<<dim3(2048),  blk, 0, stream>>>(out, muPart, covPart);
  k_mured   <<<dim3(64),    blk, 0, stream>>>(muPart, muT);
  k_finalize<<<dim3(finGrid), blk, 0, stream>>>(covPart, muT, covW, muW, cnt, covTest, covTr);
  k_ns      <<<dim3(512),   blk, 0, stream>>>(covTr, covTest, Sm, Zim);
  k_tmap    <<<dim3(256),   blk, 0, stream>>>(Zim, Sm, Tm);
  k_apply   <<<dim3(16384), blk, 0, stream>>>(out, muT, Tm, muW, A, 2);

  k_tout<<<dim3(4 * (M_/4)), blk, 0, stream>>>(A, out);
}

// Round 8
// 500.011 us; speedup vs baseline: 1.3129x; 1.1591x over previous
//
#include <hip/hip_runtime.h>

#define C_ 256
#define D_ 56
#define N_ 64
#define M_ 3584     // rows per channel (N*56), same both stages since H==W
#define DD_ 3136    // 56*56
#define PL_ 200704  // per-channel plane = M_*56
#define NS_ITERS 16

typedef __attribute__((ext_vector_type(8))) short v8s;
typedef __attribute__((ext_vector_type(8))) _Float16 v8h;
typedef __attribute__((ext_vector_type(4))) _Float16 v4h;
typedef __attribute__((ext_vector_type(4))) float v4f;

__device__ __forceinline__ unsigned short f2bf(float f) {
  union { float f; unsigned u; } x; x.f = f;
  unsigned r = x.u + 0x7FFFu + ((x.u >> 16) & 1u);
  return (unsigned short)(r >> 16);
}
__device__ __forceinline__ float bf2f(unsigned short h) {
  union { unsigned u; float f; } x; x.u = ((unsigned)h) << 16;
  return x.f;
}

// x (N,H,W,C) fp32 -> A (C, n*56+w, h) fp16. Group of 4 m's per block.
__global__ __launch_bounds__(256) void k_tin(const float* __restrict__ x, _Float16* __restrict__ A) {
  int b = blockIdx.x;
  int cchunk = b & 3, g = b >> 2;
  int c0 = cchunk * 64;
  int m0 = g * 4;
  int n = m0 / 56, w0 = m0 % 56;
  __shared__ _Float16 t[4][56][66];   // [mloc][h][cc]  29568 B
  int tid = threadIdx.x;
  const float4* x4 = (const float4*)x;
  #pragma unroll
  for (int it = 0; it < 14; ++it) {
    int i = tid + 256*it;
    int mloc = i / 896, r = i % 896;
    int h = r >> 4, cg = r & 15;
    float4 v = x4[((size_t)n*3136 + (size_t)h*56 + (w0+mloc))*64 + (c0>>2) + cg];
    t[mloc][h][4*cg+0] = (_Float16)v.x;
    t[mloc][h][4*cg+1] = (_Float16)v.y;
    t[mloc][h][4*cg+2] = (_Float16)v.z;
    t[mloc][h][4*cg+3] = (_Float16)v.w;
  }
  __syncthreads();
  #pragma unroll
  for (int it = 0; it < 7; ++it) {
    int j = tid + 256*it;
    int q = j / 7, hg = j % 7;
    int cc = q >> 2, mloc = q & 3;
    v8h o;
    #pragma unroll
    for (int k = 0; k < 8; ++k) o[k] = t[mloc][hg*8+k][cc];
    *(v8h*)&A[(size_t)(c0+cc)*PL_ + (size_t)(m0+mloc)*56 + hg*8] = o;
  }
}

// ---------- fp16-split MFMA helpers ----------
__device__ __forceinline__ void mm_split_h(const _Float16 (*Ah)[72], const _Float16 (*Al)[72],
                                           const _Float16 (*Bh)[72], const _Float16 (*Bl)[72],
                                           int w, int lr, int lq, v4f (&acc)[4]) {
  v8h ah[2], al[2], bh[4][2], bl[4][2];
  #pragma unroll
  for (int s = 0; s < 2; ++s) {
    int kb = 32*s + 8*lq;
    ah[s] = *(const v8h*)&Ah[16*w + lr][kb];
    al[s] = *(const v8h*)&Al[16*w + lr][kb];
    #pragma unroll
    for (int jt = 0; jt < 4; ++jt) {
      bh[jt][s] = *(const v8h*)&Bh[16*jt + lr][kb];
      bl[jt][s] = *(const v8h*)&Bl[16*jt + lr][kb];
    }
  }
  #pragma unroll
  for (int jt = 0; jt < 4; ++jt) {
    #pragma unroll
    for (int s = 0; s < 2; ++s) {
      acc[jt] = __builtin_amdgcn_mfma_f32_16x16x32_f16(ah[s], bh[jt][s], acc[jt], 0, 0, 0);
      acc[jt] = __builtin_amdgcn_mfma_f32_16x16x32_f16(ah[s], bl[jt][s], acc[jt], 0, 0, 0);
      acc[jt] = __builtin_amdgcn_mfma_f32_16x16x32_f16(al[s], bh[jt][s], acc[jt], 0, 0, 0);
    }
  }
}

__device__ __forceinline__ void store_split_h(_Float16 (*H)[72], _Float16 (*L)[72],
                                              int w, int lr, int lq, const v4f (&val)[4]) {
  #pragma unroll
  for (int jt = 0; jt < 4; ++jt) {
    #pragma unroll
    for (int e = 0; e < 4; ++e) {
      int i = 16*w + 4*lq + e, j = 16*jt + lr;
      float v = val[jt][e];
      _Float16 h = (_Float16)v;
      H[i][j] = h;
      L[i][j] = (_Float16)(v - (float)h);
    }
  }
}

// Fused: raw column-sum (fp32 exact) + raw second moment via split-bf16 MFMA.
// in: fp16 (C, 3584, 56). Split-bf16 of fp16 data is exact (8+8 >= 11 mantissa bits).
__global__ __launch_bounds__(256) void k_stats(const _Float16* __restrict__ in,
                                               float* __restrict__ muPart,
                                               float* __restrict__ covPart) {
  int b = blockIdx.x;
  int c = b >> 3, s = b & 7;
  const _Float16* p = in + (size_t)c*PL_ + (size_t)(s*448)*56;
  __shared__ __align__(16) char lds[18432];
  unsigned short (*At)[72]  = (unsigned short(*)[72])lds;
  unsigned short (*Alt)[72] = (unsigned short(*)[72])(lds + 9216);
  float (*Qbuf)[66] = (float(*)[66])lds;
  float (*red2)[60] = (float(*)[60])lds;   // 32 rows x 60 overlay
  int tid = threadIdx.x;
  int cg = tid % 7, rg = tid / 7;          // valid tid<224 (rg<32)
  bool act = tid < 224;
  float cs[8] = {0.f,0.f,0.f,0.f,0.f,0.f,0.f,0.f};

  int l = tid & 63, w = tid >> 6;
  int lr = l & 15, lq = l >> 4;
  v4f zero4 = {0.f, 0.f, 0.f, 0.f};
  v4f accP[4], accQ[4];
  #pragma unroll
  for (int j = 0; j < 4; ++j) { accP[j] = zero4; accQ[j] = zero4; }

  for (int ch = 0; ch < 7; ++ch) {
    __syncthreads();
    if (act) {
      #pragma unroll
      for (int u = 0; u < 2; ++u) {
        int m = rg + 32*u;
        v8h v = *(const v8h*)&p[(size_t)(ch*64 + m)*56 + cg*8];
        #pragma unroll
        for (int k = 0; k < 8; ++k) {
          float f = (float)v[k];
          cs[k] += f;
          unsigned short h = f2bf(f);
          At[cg*8+k][m] = h;
          Alt[cg*8+k][m] = f2bf(f - bf2f(h));
        }
      }
    }
    __syncthreads();
    #pragma unroll
    for (int s2 = 0; s2 < 2; ++s2) {
      int kb = 32*s2 + 8*lq;
      v8s a = *(const v8s*)&At[16*w + lr][kb];
      #pragma unroll
      for (int j = 0; j < 4; ++j) {
        v8s bh = *(const v8s*)&At[16*j + lr][kb];
        v8s bl = *(const v8s*)&Alt[16*j + lr][kb];
        accP[j] = __builtin_amdgcn_mfma_f32_16x16x32_bf16(a, bh, accP[j], 0, 0, 0);
        accQ[j] = __builtin_amdgcn_mfma_f32_16x16x32_bf16(a, bl, accQ[j], 0, 0, 0);
      }
    }
  }

  // ---- mu reduction (overlay; MFMA reads done) ----
  __syncthreads();
  if (act) {
    #pragma unroll
    for (int k = 0; k < 8; ++k) red2[rg][cg*8+k] = cs[k];
  }
  __syncthreads();
  if (tid < 64) {
    float m = 0.f;
    if (tid < 56) {
      #pragma unroll
      for (int r = 0; r < 32; ++r) m += red2[r][tid];
    }
    muPart[((size_t)s*C_ + c)*64 + tid] = m;
  }
  __syncthreads();

  // ---- epilogue: S = P + Q + Q^T ----
  #pragma unroll
  for (int j = 0; j < 4; ++j) {
    #pragma unroll
    for (int e = 0; e < 4; ++e) {
      int r = 16*w + 4*lq + e, cc = 16*j + lr;
      Qbuf[r][cc] = accQ[j][e];
    }
  }
  __syncthreads();
  float* op = covPart + ((size_t)s*C_ + c)*DD_;
  #pragma unroll
  for (int j = 0; j < 4; ++j) {
    #pragma unroll
    for (int e = 0; e < 4; ++e) {
      int r = 16*w + 4*lq + e, cc = 16*j + lr;
      if (r < 56 && cc < 56) op[r*56 + cc] = accP[j][e] + accQ[j][e] + Qbuf[cc][r];
    }
  }
}

__global__ __launch_bounds__(256) void k_mured(const float* __restrict__ muPart, float* __restrict__ muT) {
  int idx = blockIdx.x*256 + threadIdx.x;
  if (idx >= C_*64) return;
  int c = idx >> 6, lane = idx & 63;
  float s = 0.f;
  for (int p = 0; p < 8; ++p) s += muPart[((size_t)p*C_ + c)*64 + lane];
  muT[idx] = s * (1.0f/M_);
}

__global__ __launch_bounds__(256) void k_finalize(const float* __restrict__ covPart, const float* __restrict__ muT,
                                                  const float* __restrict__ covIn, const float* __restrict__ muTrn,
                                                  const int* __restrict__ counter,
                                                  float* __restrict__ covTest, float* __restrict__ covTr) {
  int idx = blockIdx.x*256 + threadIdx.x;
  const int total = C_*DD_;
  if (idx < total) {
    int c = idx / DD_, r2 = idx % DD_, i = r2/56, j = r2%56;
    float ssum = 0.f;
    for (int s = 0; s < 8; ++s) ssum += covPart[((size_t)s*C_ + c)*DD_ + r2];
    float v = ssum*(1.0f/M_) - muT[c*64+i]*muT[c*64+j];
    if (i == j) v *= 1.001f;
    covTest[idx] = v;
  } else if (idx < 2*total) {
    int k = idx - total;
    int c = k / DD_, r2 = k % DD_, i = r2/56, j = r2%56;
    float cnt = (float)counter[0];
    covTr[k] = covIn[k]/cnt - muTrn[c*56+i]*muTrn[c*56+j];
  }
}

// Coupled Newton-Schulz via fp16-split MFMA.
__global__ __launch_bounds__(256) void k_ns(const float* __restrict__ covTr, const float* __restrict__ covTest,
                                            float* __restrict__ Sout, float* __restrict__ Zout) {
  __shared__ __align__(16) _Float16 mats[6][64][72];
  __shared__ float red[4];
  int tid = threadIdx.x;
  int which = blockIdx.x & 1, c = blockIdx.x >> 1;
  const float4* Ain4 = (const float4*)((which ? covTest : covTr) + (size_t)c * DD_);

  typedef _Float16 (*mat_t)[72];
  mat_t Yh = mats[0], Yl = mats[1], Zh = mats[2], Zl = mats[3], Th = mats[4], Tl = mats[5];

  float ss = 0.f;
  for (int i4 = tid; i4 < 784; i4 += 256) {
    float4 v = Ain4[i4];
    ss += v.x*v.x + v.y*v.y + v.z*v.z + v.w*v.w;
  }
  { unsigned* z = (unsigned*)mats; for (int i = tid; i < 13824; i += 256) z[i] = 0u; }
  #pragma unroll
  for (int off = 32; off > 0; off >>= 1) ss += __shfl_down(ss, off, 64);
  if ((tid & 63) == 0) red[tid >> 6] = ss;
  __syncthreads();
  float s = sqrtf(red[0] + red[1] + red[2] + red[3]);
  float inv = 1.f / s;

  for (int i4 = tid; i4 < 784; i4 += 256) {
    float4 v = Ain4[i4];
    int r = i4 / 14, cgx = (i4 % 14) * 4;
    float f0 = v.x*inv, f1 = v.y*inv, f2 = v.z*inv, f3 = v.w*inv;
    v4h hh, ll;
    hh.x = (_Float16)f0; ll.x = (_Float16)(f0 - (float)hh.x);
    hh.y = (_Float16)f1; ll.y = (_Float16)(f1 - (float)hh.y);
    hh.z = (_Float16)f2; ll.z = (_Float16)(f2 - (float)hh.z);
    hh.w = (_Float16)f3; ll.w = (_Float16)(f3 - (float)hh.w);
    *(v4h*)&Yh[r][cgx] = hh;
    *(v4h*)&Yl[r][cgx] = ll;
  }
  if (tid < 56) Zh[tid][tid] = (_Float16)1.0f;
  __syncthreads();

  int lane = tid & 63, w = tid >> 6, lr = lane & 15, lq = lane >> 4;
  v4f zero4 = {0.f, 0.f, 0.f, 0.f};
  float rs = sqrtf(s);
  float fac = which ? (1.f/rs) : rs;
  float* outp = (which ? Zout : Sout) + (size_t)c*DD_;

  for (int it = 0; it < NS_ITERS; ++it) {
    v4f accW[4] = {zero4, zero4, zero4, zero4};
    mm_split_h(Zh, Zl, Yh, Yl, w, lr, lq, accW);
    v4f Tv[4];
    #pragma unroll
    for (int jt = 0; jt < 4; ++jt) {
      #pragma unroll
      for (int e = 0; e < 4; ++e) {
        float dv = (16*w + 4*lq + e == 16*jt + lr) ? 1.5f : 0.f;
        Tv[jt][e] = dv - 0.5f*accW[jt][e];
      }
    }
    store_split_h(Th, Tl, w, lr, lq, Tv);
    __syncthreads();
    if (it == NS_ITERS - 1) {
      v4f accF[4] = {zero4, zero4, zero4, zero4};
      if (which == 0) mm_split_h(Yh, Yl, Th, Tl, w, lr, lq, accF);
      else            mm_split_h(Th, Tl, Zh, Zl, w, lr, lq, accF);
      #pragma unroll
      for (int jt = 0; jt < 4; ++jt) {
        #pragma unroll
        for (int e = 0; e < 4; ++e) {
          int i = 16*w + 4*lq + e, j = 16*jt + lr;
          if (i < 56 && j < 56) outp[i*56 + j] = accF[jt][e] * fac;
        }
      }
    } else {
      v4f accY[4] = {zero4, zero4, zero4, zero4};
      v4f accZ[4] = {zero4, zero4, zero4, zero4};
      mm_split_h(Yh, Yl, Th, Tl, w, lr, lq, accY);
      mm_split_h(Th, Tl, Zh, Zl, w, lr, lq, accZ);
      __syncthreads();
      store_split_h(Yh, Yl, w, lr, lq, accY);
      store_split_h(Zh, Zl, w, lr, lq, accZ);
      __syncthreads();
    }
  }
}

// Tm[c] = Zi[c] @ S[c]  via fp16-split MFMA
__global__ __launch_bounds__(256) void k_tmap(const float* __restrict__ Zi, const float* __restrict__ Sm,
                                              float* __restrict__ Tm) {
  __shared__ __align__(16) _Float16 mats[4][64][72];
  int c = blockIdx.x, tid = threadIdx.x;
  typedef _Float16 (*mat_t)[72];
  mat_t Ah = mats[0], Al = mats[1], Bh = mats[2], Bl = mats[3];
  { unsigned* z = (unsigned*)mats; for (int i = tid; i < 9216; i += 256) z[i] = 0u; }
  __syncthreads();
  const float4* Z4 = (const float4*)(Zi + (size_t)c*DD_);
  const float4* S4 = (const float4*)(Sm + (size_t)c*DD_);
  for (int i4 = tid; i4 < 784; i4 += 256) {
    int r = i4 / 14, cgx = (i4 % 14) * 4;
    float4 v = Z4[i4];
    v4h hh, ll;
    hh.x = (_Float16)v.x; ll.x = (_Float16)(v.x - (float)hh.x);
    hh.y = (_Float16)v.y; ll.y = (_Float16)(v.y - (float)hh.y);
    hh.z = (_Float16)v.z; ll.z = (_Float16)(v.z - (float)hh.z);
    hh.w = (_Float16)v.w; ll.w = (_Float16)(v.w - (float)hh.w);
    *(v4h*)&Ah[r][cgx] = hh;
    *(v4h*)&Al[r][cgx] = ll;
    v = S4[i4];
    hh.x = (_Float16)v.x; ll.x = (_Float16)(v.x - (float)hh.x);
    hh.y = (_Float16)v.y; ll.y = (_Float16)(v.y - (float)hh.y);
    hh.z = (_Float16)v.z; ll.z = (_Float16)(v.z - (float)hh.z);
    hh.w = (_Float16)v.w; ll.w = (_Float16)(v.w - (float)hh.w);
    *(v4h*)&Bh[r][cgx] = hh;
    *(v4h*)&Bl[r][cgx] = ll;
  }
  __syncthreads();
  int lane = tid & 63, w = tid >> 6, lr = lane & 15, lq = lane >> 4;
  v4f zero4 = {0.f, 0.f, 0.f, 0.f};
  v4f acc[4] = {zero4, zero4, zero4, zero4};
  mm_split_h(Ah, Al, Bh, Bl, w, lr, lq, acc);
  float* op = Tm + (size_t)c*DD_;
  #pragma unroll
  for (int jt = 0; jt < 4; ++jt) {
    #pragma unroll
    for (int e = 0; e < 4; ++e) {
      int i = 16*w + 4*lq + e, j = 16*jt + lr;
      if (i < 56 && j < 56) op[i*56 + j] = acc[jt][e];
    }
  }
}

// Per-(c,n) 56x56 tile: Y = (X - muT) @ T + muTrain via fp16 MFMA, fp32 accum.
// fp16 in / fp16 out. stage 1: write out[h][w] = Y[w][h]; stage 2: out[h][w] = Y[h][w].
__global__ __launch_bounds__(256) void k_apply(const _Float16* __restrict__ in, const float* __restrict__ muT,
                                               const float* __restrict__ Tmp, const float* __restrict__ muTrain,
                                               _Float16* __restrict__ out, int stage) {
  int b = blockIdx.x;
  int c = b >> 6, n = b & 63;
  __shared__ __align__(16) char lds[18432];
  _Float16 (*Abf)[72] = (_Float16(*)[72])lds;
  _Float16 (*Tt)[72]  = (_Float16(*)[72])(lds + 9216);
  float (*Y)[67] = (float(*)[67])lds;
  __shared__ float smu[64], smt[64];
  int tid = threadIdx.x;
  if (tid < 64) {
    smu[tid] = muT[c*64 + tid];
    smt[tid] = (tid < 56) ? muTrain[c*56 + tid] : 0.f;
  }
  if (tid < 128) {
    int row = tid & 63;
    _Float16 (*Mz)[72] = (tid < 64) ? Abf : Tt;
    *(float4*)&Mz[row][56] = make_float4(0.f, 0.f, 0.f, 0.f);
  }
  __syncthreads();
  const v8h* p8 = (const v8h*)(in + (size_t)c*PL_ + (size_t)n*3136);
  const float4* t4 = (const float4*)(Tmp + (size_t)c*DD_);
  for (int i = tid; i < 392; i += 256) {
    int row = i / 7, cg = i % 7;
    v8h v = p8[row*7 + cg];
    v8h pk;
    #pragma unroll
    for (int k = 0; k < 8; ++k) pk[k] = (_Float16)((float)v[k] - smu[cg*8+k]);
    *(v8h*)&Abf[row][cg*8] = pk;
  }
  for (int i = tid; i < 784; i += 256) {
    float4 t = t4[i];
    int row = i / 14, cgx = (i % 14) * 4;
    Tt[cgx+0][row] = (_Float16)t.x;
    Tt[cgx+1][row] = (_Float16)t.y;
    Tt[cgx+2][row] = (_Float16)t.z;
    Tt[cgx+3][row] = (_Float16)t.w;
  }
  __syncthreads();
  int l = tid & 63, w = tid >> 6;
  int lr = l & 15, lq = l >> 4;
  v4f zero4 = {0.f, 0.f, 0.f, 0.f};
  v4f acc[4];
  #pragma unroll
  for (int j = 0; j < 4; ++j) acc[j] = zero4;
  #pragma unroll
  for (int s = 0; s < 2; ++s) {
    int kb = 32*s + 8*lq;
    v8h a = *(const v8h*)&Abf[16*w + lr][kb];
    #pragma unroll
    for (int j = 0; j < 4; ++j) {
      v8h bb = *(const v8h*)&Tt[16*j + lr][kb];
      acc[j] = __builtin_amdgcn_mfma_f32_16x16x32_f16(a, bb, acc[j], 0, 0, 0);
    }
  }
  __syncthreads();   // done reading tiles; overlay Y
  #pragma unroll
  for (int j = 0; j < 4; ++j) {
    #pragma unroll
    for (int e = 0; e < 4; ++e) {
      int r = 16*w + 4*lq + e, cc = 16*j + lr;
      Y[r][cc] = acc[j][e] + smt[cc];
    }
  }
  __syncthreads();
  _Float16* o16 = out + (size_t)c*PL_ + (size_t)n*3136;
  if (stage == 1) {
    for (int i = tid; i < 392; i += 256) {
      int h = i / 7, wg = i % 7;
      v8h o;
      #pragma unroll
      for (int k = 0; k < 8; ++k) o[k] = (_Float16)Y[wg*8+k][h];
      *(v8h*)&o16[h*56 + wg*8] = o;
    }
  } else {
    for (int i = tid; i < 392; i += 256) {
      int h = i / 7, wg = i % 7;
      v8h o;
      #pragma unroll
      for (int k = 0; k < 8; ++k) o[k] = (_Float16)Y[h][wg*8+k];
      *(v8h*)&o16[h*56 + wg*8] = o;
    }
  }
}

// A2 (c, n, h, w) fp16 -> out (n, h, w, c) fp32. Group of 4 nh per block.
__global__ __launch_bounds__(256) void k_tout(const _Float16* __restrict__ A2, float* __restrict__ out) {
  int b = blockIdx.x;
  int cchunk = b & 3, g = b >> 2;
  int c0 = cchunk * 64;
  int nh0 = g * 4;
  __shared__ _Float16 t[4][56][66];   // [mloc][w][cc]
  int tid = threadIdx.x;
  #pragma unroll
  for (int it = 0; it < 7; ++it) {
    int j = tid + 256*it;
    int q = j / 7, wg = j % 7;
    int cc = q >> 2, mloc = q & 3;
    v8h v = *(const v8h*)&A2[(size_t)(c0+cc)*PL_ + (size_t)(nh0+mloc)*56 + wg*8];
    #pragma unroll
    for (int k = 0; k < 8; ++k) t[mloc][wg*8+k][cc] = v[k];
  }
  __syncthreads();
  float4* o4 = (float4*)out;
  #pragma unroll
  for (int it = 0; it < 14; ++it) {
    int i = tid + 256*it;
    int mloc = i / 896, r = i % 896;
    int w = r >> 4, cg = r & 15;
    float4 o;
    o.x = (float)t[mloc][w][4*cg+0];
    o.y = (float)t[mloc][w][4*cg+1];
    o.z = (float)t[mloc][w][4*cg+2];
    o.w = (float)t[mloc][w][4*cg+3];
    o4[((size_t)(nh0+mloc)*56 + w)*64 + (c0>>2) + cg] = o;
  }
}

extern "C" void kernel_launch(void* const* d_in, const int* in_sizes, int n_in,
                              void* d_out, int out_size, void* d_ws, size_t ws_size,
                              hipStream_t stream) {
  (void)in_sizes; (void)n_in; (void)out_size;
  const float* x    = (const float*)d_in[0];
  const float* covH = (const float*)d_in[1];
  const float* muH  = (const float*)d_in[2];
  const float* covW = (const float*)d_in[3];
  const float* muW  = (const float*)d_in[4];
  const int*   cnt  = (const int*)d_in[5];
  float* out = (float*)d_out;

  char* ws = (char*)d_ws;
  size_t off = 0;
  auto allocB = [&](size_t nbytes) {
    void* p = ws + off;
    off += ((nbytes + 255) / 256) * 256;
    return p;
  };
  _Float16* A16a  = (_Float16*)allocB((size_t)C_ * PL_ * 2);
  _Float16* A16b  = (_Float16*)allocB((size_t)C_ * PL_ * 2);
  float* covPart  = (float*)allocB((size_t)8 * C_ * DD_ * 4);
  float* muPart   = (float*)allocB((size_t)8 * C_ * 64 * 4);
  float* covTest  = (float*)allocB((size_t)C_ * DD_ * 4);
  float* covTr    = (float*)allocB((size_t)C_ * DD_ * 4);
  float* Sm       = (float*)allocB((size_t)C_ * DD_ * 4);
  float* Zim      = (float*)allocB((size_t)C_ * DD_ * 4);
  float* Tm       = (float*)allocB((size_t)C_ * DD_ * 4);
  float* muT      = (float*)allocB((size_t)C_ * 64 * 4);
  if (off > ws_size) return;

  dim3 blk(256);
  const int finGrid = (2*C_*DD_ + 255)/256;

  k_tin<<<dim3(4 * (M_/4)), blk, 0, stream>>>(x, A16a);

  // ---- stage 1 (H axis) ----
  k_stats   <<<dim3(2048),  blk, 0, stream>>>(A16a, muPart, covPart);
  k_mured   <<<dim3(64),    blk, 0, stream>>>(muPart, muT);
  k_finalize<<<dim3(finGrid), blk, 0, stream>>>(covPart, muT, covH, muH, cnt, covTest, covTr);
  k_ns      <<<dim3(512),   blk, 0, stream>>>(covTr, covTest, Sm, Zim);
  k_tmap    <<<dim3(256),   blk, 0, stream>>>(Zim, Sm, Tm);
  k_apply   <<<dim3(16384), blk, 0, stream>>>(A16a, muT, Tm, muH, A16b, 1);

  // ---- stage 2 (W axis) ----
  k_stats   <<<dim3(2048),  blk, 0, stream>>>(A16b, muPart, covPart);
  k_mured   <<<dim3(64),    blk, 0, stream>>>(muPart, muT);
  k_finalize<<<dim3(finGrid), blk, 0, stream>>>(covPart, muT, covW, muW, cnt, covTest, covTr);
  k_ns      <<<dim3(512),   blk, 0, stream>>>(covTr, covTest, Sm, Zim);
  k_tmap    <<<dim3(256),   blk, 0, stream>>>(Zim, Sm, Tm);
  k_apply   <<<dim3(16384), blk, 0, stream>>>(A16b, muT, Tm, muW, A16a, 2);

  k_tout<<<dim3(4 * (M_/4)), blk, 0, stream>>>(A16a, out);
}

// Round 10
// 491.429 us; speedup vs baseline: 1.3358x; 1.0175x over previous
//
#include <hip/hip_runtime.h>

#define C_ 256
#define D_ 56
#define N_ 64
#define M_ 3584     // rows per channel (N*56), same both stages since H==W
#define DD_ 3136    // 56*56
#define PL_ 200704  // per-channel plane = M_*56
#define NS_ITERS 16

typedef __attribute__((ext_vector_type(8))) short v8s;
typedef __attribute__((ext_vector_type(8))) _Float16 v8h;
typedef __attribute__((ext_vector_type(4))) _Float16 v4h;
typedef __attribute__((ext_vector_type(4))) float v4f;

__device__ __forceinline__ unsigned short f2bf(float f) {
  union { float f; unsigned u; } x; x.f = f;
  unsigned r = x.u + 0x7FFFu + ((x.u >> 16) & 1u);
  return (unsigned short)(r >> 16);
}
__device__ __forceinline__ float bf2f(unsigned short h) {
  union { unsigned u; float f; } x; x.u = ((unsigned)h) << 16;
  return x.f;
}

// x (N,H,W,C) fp32 -> A (C, n*56+w, h) fp16. Group of 4 m's per block.
__global__ __launch_bounds__(256) void k_tin(const float* __restrict__ x, _Float16* __restrict__ A) {
  int b = blockIdx.x;
  int cchunk = b & 3, g = b >> 2;
  int c0 = cchunk * 64;
  int m0 = g * 4;
  int n = m0 / 56, w0 = m0 % 56;
  __shared__ _Float16 t[4][56][66];   // [mloc][h][cc]  29568 B
  int tid = threadIdx.x;
  const float4* x4 = (const float4*)x;
  #pragma unroll
  for (int it = 0; it < 14; ++it) {
    int i = tid + 256*it;
    int mloc = i / 896, r = i % 896;
    int h = r >> 4, cg = r & 15;
    float4 v = x4[((size_t)n*3136 + (size_t)h*56 + (w0+mloc))*64 + (c0>>2) + cg];
    t[mloc][h][4*cg+0] = (_Float16)v.x;
    t[mloc][h][4*cg+1] = (_Float16)v.y;
    t[mloc][h][4*cg+2] = (_Float16)v.z;
    t[mloc][h][4*cg+3] = (_Float16)v.w;
  }
  __syncthreads();
  #pragma unroll
  for (int it = 0; it < 7; ++it) {
    int j = tid + 256*it;
    int q = j / 7, hg = j % 7;
    int cc = q >> 2, mloc = q & 3;
    v8h o;
    #pragma unroll
    for (int k = 0; k < 8; ++k) o[k] = t[mloc][hg*8+k][cc];
    *(v8h*)&A[(size_t)(c0+cc)*PL_ + (size_t)(m0+mloc)*56 + hg*8] = o;
  }
}

// ---------- fp16-split MFMA helpers ----------
__device__ __forceinline__ void mm_split_h(const _Float16 (*Ah)[72], const _Float16 (*Al)[72],
                                           const _Float16 (*Bh)[72], const _Float16 (*Bl)[72],
                                           int w, int lr, int lq, v4f (&acc)[4]) {
  v8h ah[2], al[2], bh[4][2], bl[4][2];
  #pragma unroll
  for (int s = 0; s < 2; ++s) {
    int kb = 32*s + 8*lq;
    ah[s] = *(const v8h*)&Ah[16*w + lr][kb];
    al[s] = *(const v8h*)&Al[16*w + lr][kb];
    #pragma unroll
    for (int jt = 0; jt < 4; ++jt) {
      bh[jt][s] = *(const v8h*)&Bh[16*jt + lr][kb];
      bl[jt][s] = *(const v8h*)&Bl[16*jt + lr][kb];
    }
  }
  #pragma unroll
  for (int jt = 0; jt < 4; ++jt) {
    #pragma unroll
    for (int s = 0; s < 2; ++s) {
      acc[jt] = __builtin_amdgcn_mfma_f32_16x16x32_f16(ah[s], bh[jt][s], acc[jt], 0, 0, 0);
      acc[jt] = __builtin_amdgcn_mfma_f32_16x16x32_f16(ah[s], bl[jt][s], acc[jt], 0, 0, 0);
      acc[jt] = __builtin_amdgcn_mfma_f32_16x16x32_f16(al[s], bh[jt][s], acc[jt], 0, 0, 0);
    }
  }
}

__device__ __forceinline__ void store_split_h(_Float16 (*H)[72], _Float16 (*L)[72],
                                              int w, int lr, int lq, const v4f (&val)[4]) {
  #pragma unroll
  for (int jt = 0; jt < 4; ++jt) {
    #pragma unroll
    for (int e = 0; e < 4; ++e) {
      int i = 16*w + 4*lq + e, j = 16*jt + lr;
      float v = val[jt][e];
      _Float16 h = (_Float16)v;
      H[i][j] = h;
      L[i][j] = (_Float16)(v - (float)h);
    }
  }
}

// Fused: raw column-sum (fp32 exact) + raw second moment via split-bf16 MFMA.
// in: fp16 (C, 3584, 56). Split-bf16 of fp16 data is exact (8+8 >= 11 mantissa bits).
// Register prefetch of chunk ch+1 overlaps the MFMA phase of chunk ch.
__global__ __launch_bounds__(256) void k_stats(const _Float16* __restrict__ in,
                                               float* __restrict__ muPart,
                                               float* __restrict__ covPart) {
  int b = blockIdx.x;
  int c = b >> 3, s = b & 7;
  const _Float16* p = in + (size_t)c*PL_ + (size_t)(s*448)*56;
  __shared__ __align__(16) char lds[18432];
  unsigned short (*At)[72]  = (unsigned short(*)[72])lds;
  unsigned short (*Alt)[72] = (unsigned short(*)[72])(lds + 9216);
  float (*Qbuf)[66] = (float(*)[66])lds;
  float (*red2)[60] = (float(*)[60])lds;   // 32 rows x 60 overlay
  int tid = threadIdx.x;
  int cg = tid % 7, rg = tid / 7;          // valid tid<224 (rg<32)
  bool act = tid < 224;
  float cs[8] = {0.f,0.f,0.f,0.f,0.f,0.f,0.f,0.f};

  int l = tid & 63, w = tid >> 6;
  int lr = l & 15, lq = l >> 4;
  v4f zero4 = {0.f, 0.f, 0.f, 0.f};
  v4f accP[4], accQ[4];
  #pragma unroll
  for (int j = 0; j < 4; ++j) { accP[j] = zero4; accQ[j] = zero4; }

  v8h pre[2];
  if (act) {
    #pragma unroll
    for (int u = 0; u < 2; ++u)
      pre[u] = *(const v8h*)&p[(size_t)(rg + 32*u)*56 + cg*8];
  }
  for (int ch = 0; ch < 7; ++ch) {
    if (act) {
      #pragma unroll
      for (int u = 0; u < 2; ++u) {
        int m = rg + 32*u;
        v8h v = pre[u];
        #pragma unroll
        for (int k = 0; k < 8; ++k) {
          float f = (float)v[k];
          cs[k] += f;
          unsigned short h = f2bf(f);
          At[cg*8+k][m] = h;
          Alt[cg*8+k][m] = f2bf(f - bf2f(h));
        }
      }
    }
    __syncthreads();                       // staging complete
    if (ch < 6 && act) {                   // issue next chunk; latency hides under MFMA
      #pragma unroll
      for (int u = 0; u < 2; ++u)
        pre[u] = *(const v8h*)&p[(size_t)((ch+1)*64 + rg + 32*u)*56 + cg*8];
    }
    #pragma unroll
    for (int s2 = 0; s2 < 2; ++s2) {
      int kb = 32*s2 + 8*lq;
      v8s a = *(const v8s*)&At[16*w + lr][kb];
      #pragma unroll
      for (int j = 0; j < 4; ++j) {
        v8s bh = *(const v8s*)&At[16*j + lr][kb];
        v8s bl = *(const v8s*)&Alt[16*j + lr][kb];
        accP[j] = __builtin_amdgcn_mfma_f32_16x16x32_bf16(a, bh, accP[j], 0, 0, 0);
        accQ[j] = __builtin_amdgcn_mfma_f32_16x16x32_bf16(a, bl, accQ[j], 0, 0, 0);
      }
    }
    __syncthreads();                       // MFMA reads done; LDS free
  }

  // ---- mu reduction (overlay; MFMA reads done) ----
  if (act) {
    #pragma unroll
    for (int k = 0; k < 8; ++k) red2[rg][cg*8+k] = cs[k];
  }
  __syncthreads();
  if (tid < 64) {
    float m = 0.f;
    if (tid < 56) {
      #pragma unroll
      for (int r = 0; r < 32; ++r) m += red2[r][tid];
    }
    muPart[((size_t)s*C_ + c)*64 + tid] = m;
  }
  __syncthreads();

  // ---- epilogue: S = P + Q + Q^T ----
  #pragma unroll
  for (int j = 0; j < 4; ++j) {
    #pragma unroll
    for (int e = 0; e < 4; ++e) {
      int r = 16*w + 4*lq + e, cc = 16*j + lr;
      Qbuf[r][cc] = accQ[j][e];
    }
  }
  __syncthreads();
  float* op = covPart + ((size_t)s*C_ + c)*DD_;
  #pragma unroll
  for (int j = 0; j < 4; ++j) {
    #pragma unroll
    for (int e = 0; e < 4; ++e) {
      int r = 16*w + 4*lq + e, cc = 16*j + lr;
      if (r < 56 && cc < 56) op[r*56 + cc] = accP[j][e] + accQ[j][e] + Qbuf[cc][r];
    }
  }
}

__global__ __launch_bounds__(256) void k_mured(const float* __restrict__ muPart, float* __restrict__ muT) {
  int idx = blockIdx.x*256 + threadIdx.x;
  if (idx >= C_*64) return;
  int c = idx >> 6, lane = idx & 63;
  float s = 0.f;
  for (int p = 0; p < 8; ++p) s += muPart[((size_t)p*C_ + c)*64 + lane];
  muT[idx] = s * (1.0f/M_);
}

__global__ __launch_bounds__(256) void k_finalize(const float* __restrict__ covPart, const float* __restrict__ muT,
                                                  const float* __restrict__ covIn, const float* __restrict__ muTrn,
                                                  const int* __restrict__ counter,
                                                  float* __restrict__ covTest, float* __restrict__ covTr) {
  int idx = blockIdx.x*256 + threadIdx.x;
  const int total = C_*DD_;
  if (idx < total) {
    int c = idx / DD_, r2 = idx % DD_, i = r2/56, j = r2%56;
    float ssum = 0.f;
    for (int s = 0; s < 8; ++s) ssum += covPart[((size_t)s*C_ + c)*DD_ + r2];
    float v = ssum*(1.0f/M_) - muT[c*64+i]*muT[c*64+j];
    if (i == j) v *= 1.001f;
    covTest[idx] = v;
  } else if (idx < 2*total) {
    int k = idx - total;
    int c = k / DD_, r2 = k % DD_, i = r2/56, j = r2%56;
    float cnt = (float)counter[0];
    covTr[k] = covIn[k]/cnt - muTrn[c*56+i]*muTrn[c*56+j];
  }
}

// Coupled Newton-Schulz via fp16-split MFMA.
__global__ __launch_bounds__(256) void k_ns(const float* __restrict__ covTr, const float* __restrict__ covTest,
                                            float* __restrict__ Sout, float* __restrict__ Zout) {
  __shared__ __align__(16) _Float16 mats[6][64][72];
  __shared__ float red[4];
  int tid = threadIdx.x;
  int which = blockIdx.x & 1, c = blockIdx.x >> 1;
  const float4* Ain4 = (const float4*)((which ? covTest : covTr) + (size_t)c * DD_);

  typedef _Float16 (*mat_t)[72];
  mat_t Yh = mats[0], Yl = mats[1], Zh = mats[2], Zl = mats[3], Th = mats[4], Tl = mats[5];

  float ss = 0.f;
  for (int i4 = tid; i4 < 784; i4 += 256) {
    float4 v = Ain4[i4];
    ss += v.x*v.x + v.y*v.y + v.z*v.z + v.w*v.w;
  }
  { unsigned* z = (unsigned*)mats; for (int i = tid; i < 13824; i += 256) z[i] = 0u; }
  #pragma unroll
  for (int off = 32; off > 0; off >>= 1) ss += __shfl_down(ss, off, 64);
  if ((tid & 63) == 0) red[tid >> 6] = ss;
  __syncthreads();
  float s = sqrtf(red[0] + red[1] + red[2] + red[3]);
  float inv = 1.f / s;

  for (int i4 = tid; i4 < 784; i4 += 256) {
    float4 v = Ain4[i4];
    int r = i4 / 14, cgx = (i4 % 14) * 4;
    float f0 = v.x*inv, f1 = v.y*inv, f2 = v.z*inv, f3 = v.w*inv;
    v4h hh, ll;
    hh.x = (_Float16)f0; ll.x = (_Float16)(f0 - (float)hh.x);
    hh.y = (_Float16)f1; ll.y = (_Float16)(f1 - (float)hh.y);
    hh.z = (_Float16)f2; ll.z = (_Float16)(f2 - (float)hh.z);
    hh.w = (_Float16)f3; ll.w = (_Float16)(f3 - (float)hh.w);
    *(v4h*)&Yh[r][cgx] = hh;
    *(v4h*)&Yl[r][cgx] = ll;
  }
  if (tid < 56) Zh[tid][tid] = (_Float16)1.0f;
  __syncthreads();

  int lane = tid & 63, w = tid >> 6, lr = lane & 15, lq = lane >> 4;
  v4f zero4 = {0.f, 0.f, 0.f, 0.f};
  float rs = sqrtf(s);
  float fac = which ? (1.f/rs) : rs;
  float* outp = (which ? Zout : Sout) + (size_t)c*DD_;

  for (int it = 0; it < NS_ITERS; ++it) {
    v4f accW[4] = {zero4, zero4, zero4, zero4};
    mm_split_h(Zh, Zl, Yh, Yl, w, lr, lq, accW);
    v4f Tv[4];
    #pragma unroll
    for (int jt = 0; jt < 4; ++jt) {
      #pragma unroll
      for (int e = 0; e < 4; ++e) {
        float dv = (16*w + 4*lq + e == 16*jt + lr) ? 1.5f : 0.f;
        Tv[jt][e] = dv - 0.5f*accW[jt][e];
      }
    }
    store_split_h(Th, Tl, w, lr, lq, Tv);
    __syncthreads();
    if (it == NS_ITERS - 1) {
      v4f accF[4] = {zero4, zero4, zero4, zero4};
      if (which == 0) mm_split_h(Yh, Yl, Th, Tl, w, lr, lq, accF);
      else            mm_split_h(Th, Tl, Zh, Zl, w, lr, lq, accF);
      #pragma unroll
      for (int jt = 0; jt < 4; ++jt) {
        #pragma unroll
        for (int e = 0; e < 4; ++e) {
          int i = 16*w + 4*lq + e, j = 16*jt + lr;
          if (i < 56 && j < 56) outp[i*56 + j] = accF[jt][e] * fac;
        }
      }
    } else {
      v4f accY[4] = {zero4, zero4, zero4, zero4};
      v4f accZ[4] = {zero4, zero4, zero4, zero4};
      mm_split_h(Yh, Yl, Th, Tl, w, lr, lq, accY);
      mm_split_h(Th, Tl, Zh, Zl, w, lr, lq, accZ);
      __syncthreads();
      store_split_h(Yh, Yl, w, lr, lq, accY);
      store_split_h(Zh, Zl, w, lr, lq, accZ);
      __syncthreads();
    }
  }
}

// Tm[c] = Zi[c] @ S[c]  via fp16-split MFMA
__global__ __launch_bounds__(256) void k_tmap(const float* __restrict__ Zi, const float* __restrict__ Sm,
                                              float* __restrict__ Tm) {
  __shared__ __align__(16) _Float16 mats[4][64][72];
  int c = blockIdx.x, tid = threadIdx.x;
  typedef _Float16 (*mat_t)[72];
  mat_t Ah = mats[0], Al = mats[1], Bh = mats[2], Bl = mats[3];
  { unsigned* z = (unsigned*)mats; for (int i = tid; i < 9216; i += 256) z[i] = 0u; }
  __syncthreads();
  const float4* Z4 = (const float4*)(Zi + (size_t)c*DD_);
  const float4* S4 = (const float4*)(Sm + (size_t)c*DD_);
  for (int i4 = tid; i4 < 784; i4 += 256) {
    int r = i4 / 14, cgx = (i4 % 14) * 4;
    float4 v = Z4[i4];
    v4h hh, ll;
    hh.x = (_Float16)v.x; ll.x = (_Float16)(v.x - (float)hh.x);
    hh.y = (_Float16)v.y; ll.y = (_Float16)(v.y - (float)hh.y);
    hh.z = (_Float16)v.z; ll.z = (_Float16)(v.z - (float)hh.z);
    hh.w = (_Float16)v.w; ll.w = (_Float16)(v.w - (float)hh.w);
    *(v4h*)&Ah[r][cgx] = hh;
    *(v4h*)&Al[r][cgx] = ll;
    v = S4[i4];
    hh.x = (_Float16)v.x; ll.x = (_Float16)(v.x - (float)hh.x);
    hh.y = (_Float16)v.y; ll.y = (_Float16)(v.y - (float)hh.y);
    hh.z = (_Float16)v.z; ll.z = (_Float16)(v.z - (float)hh.z);
    hh.w = (_Float16)v.w; ll.w = (_Float16)(v.w - (float)hh.w);
    *(v4h*)&Bh[r][cgx] = hh;
    *(v4h*)&Bl[r][cgx] = ll;
  }
  __syncthreads();
  int lane = tid & 63, w = tid >> 6, lr = lane & 15, lq = lane >> 4;
  v4f zero4 = {0.f, 0.f, 0.f, 0.f};
  v4f acc[4] = {zero4, zero4, zero4, zero4};
  mm_split_h(Ah, Al, Bh, Bl, w, lr, lq, acc);
  float* op = Tm + (size_t)c*DD_;
  #pragma unroll
  for (int jt = 0; jt < 4; ++jt) {
    #pragma unroll
    for (int e = 0; e < 4; ++e) {
      int i = 16*w + 4*lq + e, j = 16*jt + lr;
      if (i < 56 && j < 56) op[i*56 + j] = acc[jt][e];
    }
  }
}

// 4 tiles per block: Y = (X - muT) @ T + muTrain via fp16 MFMA, fp32 accum.
// T staged once per block; next tile's X prefetched to regs under current MFMA.
// fp16 in / fp16 out. stage 1: out[h][w] = Y[w][h]; stage 2: out[h][w] = Y[h][w].
__global__ __launch_bounds__(256) void k_apply(const _Float16* __restrict__ in, const float* __restrict__ muT,
                                               const float* __restrict__ Tmp, const float* __restrict__ muTrain,
                                               _Float16* __restrict__ out, int stage) {
  int b = blockIdx.x;
  int c = b >> 4, ng = b & 15;
  int n0 = ng * 4;
  __shared__ __align__(16) _Float16 Abf[64][72];   // X tile [m][k]
  __shared__ __align__(16) _Float16 Tt[64][72];    // T^T [f][k]
  __shared__ float Y[56][57];                      // result tile
  __shared__ float smu[64], smt[64];
  int tid = threadIdx.x;
  if (tid < 64) {
    smu[tid] = muT[c*64 + tid];
    smt[tid] = (tid < 56) ? muTrain[c*56 + tid] : 0.f;
  }
  if (tid < 128) {   // zero K-pad cols [56:64) once; cols 0..55 rewritten per tile
    int row = tid & 63;
    _Float16 (*Mz)[72] = (tid < 64) ? Abf : Tt;
    *(float4*)&Mz[row][56] = make_float4(0.f, 0.f, 0.f, 0.f);
  }
  // T stage (once per block)
  const float4* t4 = (const float4*)(Tmp + (size_t)c*DD_);
  for (int i = tid; i < 784; i += 256) {
    float4 t = t4[i];
    int row = i / 14, cgx = (i % 14) * 4;
    Tt[cgx+0][row] = (_Float16)t.x;
    Tt[cgx+1][row] = (_Float16)t.y;
    Tt[cgx+2][row] = (_Float16)t.z;
    Tt[cgx+3][row] = (_Float16)t.w;
  }
  int l = tid & 63, w = tid >> 6;
  int lr = l & 15, lq = l >> 4;
  v4f zero4 = {0.f, 0.f, 0.f, 0.f};
  const v8h* p8base = (const v8h*)(in + (size_t)c*PL_);

  v8h preA[2], preB[2];
  {
    const v8h* p8 = p8base + (size_t)n0*392;
    #pragma unroll
    for (int u = 0; u < 2; ++u) { int i = tid + 256*u; if (i < 392) preA[u] = p8[i]; }
  }
  for (int t = 0; t < 4; ++t) {
    // stage X tile t (centered)
    #pragma unroll
    for (int u = 0; u < 2; ++u) {
      int i = tid + 256*u;
      if (i < 392) {
        int row = i / 7, cg = i % 7;
        v8h pk;
        #pragma unroll
        for (int k = 0; k < 8; ++k) pk[k] = (_Float16)((float)preA[u][k] - smu[cg*8+k]);
        *(v8h*)&Abf[row][cg*8] = pk;
      }
    }
    __syncthreads();
    if (t < 3) {   // prefetch tile t+1 (latency hides under MFMA)
      const v8h* p8 = p8base + (size_t)(n0+t+1)*392;
      #pragma unroll
      for (int u = 0; u < 2; ++u) { int i = tid + 256*u; if (i < 392) preB[u] = p8[i]; }
    }
    v4f acc[4] = {zero4, zero4, zero4, zero4};
    #pragma unroll
    for (int s = 0; s < 2; ++s) {
      int kb = 32*s + 8*lq;
      v8h a = *(const v8h*)&Abf[16*w + lr][kb];
      #pragma unroll
      for (int j = 0; j < 4; ++j) {
        v8h bb = *(const v8h*)&Tt[16*j + lr][kb];
        acc[j] = __builtin_amdgcn_mfma_f32_16x16x32_f16(a, bb, acc[j], 0, 0, 0);
      }
    }
    __syncthreads();   // done reading Abf (and Y readers from prev tile are done)
    #pragma unroll
    for (int j = 0; j < 4; ++j) {
      #pragma unroll
      for (int e = 0; e < 4; ++e) {
        int r = 16*w + 4*lq + e, cc = 16*j + lr;
        if (r < 56 && cc < 56) Y[r][cc] = acc[j][e] + smt[cc];
      }
    }
    __syncthreads();   // Y complete
    _Float16* o16 = out + (size_t)c*PL_ + (size_t)(n0+t)*3136;
    if (stage == 1) {
      for (int i = tid; i < 392; i += 256) {
        int h = i / 7, wg = i % 7;
        v8h o;
        #pragma unroll
        for (int k = 0; k < 8; ++k) o[k] = (_Float16)Y[wg*8+k][h];
        *(v8h*)&o16[h*56 + wg*8] = o;
      }
    } else {
      for (int i = tid; i < 392; i += 256) {
        int h = i / 7, wg = i % 7;
        v8h o;
        #pragma unroll
        for (int k = 0; k < 8; ++k) o[k] = (_Float16)Y[h][wg*8+k];
        *(v8h*)&o16[h*56 + wg*8] = o;
      }
    }
    preA[0] = preB[0]; preA[1] = preB[1];
  }
}

// A2 (c, n, h, w) fp16 -> out (n, h, w, c) fp32. Group of 4 nh per block.
__global__ __launch_bounds__(256) void k_tout(const _Float16* __restrict__ A2, float* __restrict__ out) {
  int b = blockIdx.x;
  int cchunk = b & 3, g = b >> 2;
  int c0 = cchunk * 64;
  int nh0 = g * 4;
  __shared__ _Float16 t[4][56][66];   // [mloc][w][cc]
  int tid = threadIdx.x;
  #pragma unroll
  for (int it = 0; it < 7; ++it) {
    int j = tid + 256*it;
    int q = j / 7, wg = j % 7;
    int cc = q >> 2, mloc = q & 3;
    v8h v = *(const v8h*)&A2[(size_t)(c0+cc)*PL_ + (size_t)(nh0+mloc)*56 + wg*8];
    #pragma unroll
    for (int k = 0; k < 8; ++k) t[mloc][wg*8+k][cc] = v[k];
  }
  __syncthreads();
  float4* o4 = (float4*)out;
  #pragma unroll
  for (int it = 0; it < 14; ++it) {
    int i = tid + 256*it;
    int mloc = i / 896, r = i % 896;
    int w = r >> 4, cg = r & 15;
    float4 o;
    o.x = (float)t[mloc][w][4*cg+0];
    o.y = (float)t[mloc][w][4*cg+1];
    o.z = (float)t[mloc][w][4*cg+2];
    o.w = (float)t[mloc][w][4*cg+3];
    o4[((size_t)(nh0+mloc)*56 + w)*64 + (c0>>2) + cg] = o;
  }
}

extern "C" void kernel_launch(void* const* d_in, const int* in_sizes, int n_in,
                              void* d_out, int out_size, void* d_ws, size_t ws_size,
                              hipStream_t stream) {
  (void)in_sizes; (void)n_in; (void)out_size;
  const float* x    = (const float*)d_in[0];
  const float* covH = (const float*)d_in[1];
  const float* muH  = (const float*)d_in[2];
  const float* covW = (const float*)d_in[3];
  const float* muW  = (const float*)d_in[4];
  const int*   cnt  = (const int*)d_in[5];
  float* out = (float*)d_out;

  char* ws = (char*)d_ws;
  size_t off = 0;
  auto allocB = [&](size_t nbytes) {
    void* p = ws + off;
    off += ((nbytes + 255) / 256) * 256;
    return p;
  };
  _Float16* A16a  = (_Float16*)allocB((size_t)C_ * PL_ * 2);
  _Float16* A16b  = (_Float16*)allocB((size_t)C_ * PL_ * 2);
  float* covPart  = (float*)allocB((size_t)8 * C_ * DD_ * 4);
  float* muPart   = (float*)allocB((size_t)8 * C_ * 64 * 4);
  float* covTest  = (float*)allocB((size_t)C_ * DD_ * 4);
  float* covTr    = (float*)allocB((size_t)C_ * DD_ * 4);
  float* Sm       = (float*)allocB((size_t)C_ * DD_ * 4);
  float* Zim      = (float*)allocB((size_t)C_ * DD_ * 4);
  float* Tm       = (float*)allocB((size_t)C_ * DD_ * 4);
  float* muT      = (float*)allocB((size_t)C_ * 64 * 4);
  if (off > ws_size) return;

  dim3 blk(256);
  const int finGrid = (2*C_*DD_ + 255)/256;

  k_tin<<<dim3(4 * (M_/4)), blk, 0, stream>>>(x, A16a);

  // ---- stage 1 (H axis) ----
  k_stats   <<<dim3(2048),  blk, 0, stream>>>(A16a, muPart, covPart);
  k_mured   <<<dim3(64),    blk, 0, stream>>>(muPart, muT);
  k_finalize<<<dim3(finGrid), blk, 0, stream>>>(covPart, muT, covH, muH, cnt, covTest, covTr);
  k_ns      <<<dim3(512),   blk, 0, stream>>>(covTr, covTest, Sm, Zim);
  k_tmap    <<<dim3(256),   blk, 0, stream>>>(Zim, Sm, Tm);
  k_apply   <<<dim3(4096),  blk, 0, stream>>>(A16a, muT, Tm, muH, A16b, 1);

  // ---- stage 2 (W axis) ----
  k_stats   <<<dim3(2048),  blk, 0, stream>>>(A16b, muPart, covPart);
  k_mured   <<<dim3(64),    blk, 0, stream>>>(muPart, muT);
  k_finalize<<<dim3(finGrid), blk, 0, stream>>>(covPart, muT, covW, muW, cnt, covTest, covTr);
  k_ns      <<<dim3(512),   blk, 0, stream>>>(covTr, covTest, Sm, Zim);
  k_tmap    <<<dim3(256),   blk, 0, stream>>>(Zim, Sm, Tm);
  k_apply   <<<dim3(4096),  blk, 0, stream>>>(A16b, muT, Tm, muW, A16a, 2);

  k_tout<<<dim3(4 * (M_/4)), blk, 0, stream>>>(A16a, out);
}

// Round 12
// 473.044 us; speedup vs baseline: 1.3877x; 1.0389x over previous
//
#include <hip/hip_runtime.h>

#define C_ 256
#define D_ 56
#define N_ 64
#define M_ 3584     // rows per channel (N*56), same both stages since H==W
#define DD_ 3136    // 56*56
#define PL_ 200704  // per-channel plane = M_*56
#define NS_ITERS 16

typedef __attribute__((ext_vector_type(8))) short v8s;
typedef __attribute__((ext_vector_type(8))) _Float16 v8h;
typedef __attribute__((ext_vector_type(4))) _Float16 v4h;
typedef __attribute__((ext_vector_type(4))) float v4f;

__device__ __forceinline__ unsigned short f2bf(float f) {
  union { float f; unsigned u; } x; x.f = f;
  unsigned r = x.u + 0x7FFFu + ((x.u >> 16) & 1u);
  return (unsigned short)(r >> 16);
}
__device__ __forceinline__ float bf2f(unsigned short h) {
  union { unsigned u; float f; } x; x.u = ((unsigned)h) << 16;
  return x.f;
}

// x (N,H,W,C) fp32 -> A (C, n*56+w, h) fp16. Group of 4 m's per block.
__global__ __launch_bounds__(256) void k_tin(const float* __restrict__ x, _Float16* __restrict__ A) {
  int b = blockIdx.x;
  int cchunk = b & 3, g = b >> 2;
  int c0 = cchunk * 64;
  int m0 = g * 4;
  int n = m0 / 56, w0 = m0 % 56;
  __shared__ _Float16 t[4][56][66];   // [mloc][h][cc]  29568 B
  int tid = threadIdx.x;
  const float4* x4 = (const float4*)x;
  #pragma unroll
  for (int it = 0; it < 14; ++it) {
    int i = tid + 256*it;
    int mloc = i / 896, r = i % 896;
    int h = r >> 4, cg = r & 15;
    float4 v = x4[((size_t)n*3136 + (size_t)h*56 + (w0+mloc))*64 + (c0>>2) + cg];
    t[mloc][h][4*cg+0] = (_Float16)v.x;
    t[mloc][h][4*cg+1] = (_Float16)v.y;
    t[mloc][h][4*cg+2] = (_Float16)v.z;
    t[mloc][h][4*cg+3] = (_Float16)v.w;
  }
  __syncthreads();
  #pragma unroll
  for (int it = 0; it < 7; ++it) {
    int j = tid + 256*it;
    int q = j / 7, hg = j % 7;
    int cc = q >> 2, mloc = q & 3;
    v8h o;
    #pragma unroll
    for (int k = 0; k < 8; ++k) o[k] = t[mloc][hg*8+k][cc];
    *(v8h*)&A[(size_t)(c0+cc)*PL_ + (size_t)(m0+mloc)*56 + hg*8] = o;
  }
}

// ---------- fp16-split MFMA helpers ----------
__device__ __forceinline__ void mm_split_h(const _Float16 (*Ah)[72], const _Float16 (*Al)[72],
                                           const _Float16 (*Bh)[72], const _Float16 (*Bl)[72],
                                           int w, int lr, int lq, v4f (&acc)[4]) {
  v8h ah[2], al[2], bh[4][2], bl[4][2];
  #pragma unroll
  for (int s = 0; s < 2; ++s) {
    int kb = 32*s + 8*lq;
    ah[s] = *(const v8h*)&Ah[16*w + lr][kb];
    al[s] = *(const v8h*)&Al[16*w + lr][kb];
    #pragma unroll
    for (int jt = 0; jt < 4; ++jt) {
      bh[jt][s] = *(const v8h*)&Bh[16*jt + lr][kb];
      bl[jt][s] = *(const v8h*)&Bl[16*jt + lr][kb];
    }
  }
  #pragma unroll
  for (int jt = 0; jt < 4; ++jt) {
    #pragma unroll
    for (int s = 0; s < 2; ++s) {
      acc[jt] = __builtin_amdgcn_mfma_f32_16x16x32_f16(ah[s], bh[jt][s], acc[jt], 0, 0, 0);
      acc[jt] = __builtin_amdgcn_mfma_f32_16x16x32_f16(ah[s], bl[jt][s], acc[jt], 0, 0, 0);
      acc[jt] = __builtin_amdgcn_mfma_f32_16x16x32_f16(al[s], bh[jt][s], acc[jt], 0, 0, 0);
    }
  }
}

__device__ __forceinline__ void store_split_h(_Float16 (*H)[72], _Float16 (*L)[72],
                                              int w, int lr, int lq, const v4f (&val)[4]) {
  #pragma unroll
  for (int jt = 0; jt < 4; ++jt) {
    #pragma unroll
    for (int e = 0; e < 4; ++e) {
      int i = 16*w + 4*lq + e, j = 16*jt + lr;
      float v = val[jt][e];
      _Float16 h = (_Float16)v;
      H[i][j] = h;
      L[i][j] = (_Float16)(v - (float)h);
    }
  }
}

// Fused: raw column-sum (fp32 exact) + raw second moment via split-bf16 MFMA.
// SPLITS=4: block = (c, s), 896 rows each (14 chunks of 64).
__global__ __launch_bounds__(256) void k_stats(const _Float16* __restrict__ in,
                                               float* __restrict__ muPart,
                                               float* __restrict__ covPart) {
  int b = blockIdx.x;
  int c = b >> 2, s = b & 3;
  const _Float16* p = in + (size_t)c*PL_ + (size_t)(s*896)*56;
  __shared__ __align__(16) char lds[18432];
  unsigned short (*At)[72]  = (unsigned short(*)[72])lds;
  unsigned short (*Alt)[72] = (unsigned short(*)[72])(lds + 9216);
  float (*Qbuf)[66] = (float(*)[66])lds;
  float (*red2)[60] = (float(*)[60])lds;   // 32 rows x 60 overlay
  int tid = threadIdx.x;
  int cg = tid % 7, rg = tid / 7;          // valid tid<224 (rg<32)
  bool act = tid < 224;
  float cs[8] = {0.f,0.f,0.f,0.f,0.f,0.f,0.f,0.f};

  int l = tid & 63, w = tid >> 6;
  int lr = l & 15, lq = l >> 4;
  v4f zero4 = {0.f, 0.f, 0.f, 0.f};
  v4f accP[4], accQ[4];
  #pragma unroll
  for (int j = 0; j < 4; ++j) { accP[j] = zero4; accQ[j] = zero4; }

  v8h pre[2];
  if (act) {
    #pragma unroll
    for (int u = 0; u < 2; ++u)
      pre[u] = *(const v8h*)&p[(size_t)(rg + 32*u)*56 + cg*8];
  }
  for (int ch = 0; ch < 14; ++ch) {
    if (act) {
      #pragma unroll
      for (int u = 0; u < 2; ++u) {
        int m = rg + 32*u;
        v8h v = pre[u];
        #pragma unroll
        for (int k = 0; k < 8; ++k) {
          float f = (float)v[k];
          cs[k] += f;
          unsigned short h = f2bf(f);
          At[cg*8+k][m] = h;
          Alt[cg*8+k][m] = f2bf(f - bf2f(h));
        }
      }
    }
    __syncthreads();                       // staging complete
    if (ch < 13 && act) {                  // issue next chunk; latency hides under MFMA
      #pragma unroll
      for (int u = 0; u < 2; ++u)
        pre[u] = *(const v8h*)&p[(size_t)((ch+1)*64 + rg + 32*u)*56 + cg*8];
    }
    #pragma unroll
    for (int s2 = 0; s2 < 2; ++s2) {
      int kb = 32*s2 + 8*lq;
      v8s a = *(const v8s*)&At[16*w + lr][kb];
      #pragma unroll
      for (int j = 0; j < 4; ++j) {
        v8s bh = *(const v8s*)&At[16*j + lr][kb];
        v8s bl = *(const v8s*)&Alt[16*j + lr][kb];
        accP[j] = __builtin_amdgcn_mfma_f32_16x16x32_bf16(a, bh, accP[j], 0, 0, 0);
        accQ[j] = __builtin_amdgcn_mfma_f32_16x16x32_bf16(a, bl, accQ[j], 0, 0, 0);
      }
    }
    __syncthreads();                       // MFMA reads done; LDS free
  }

  // ---- mu reduction (overlay; MFMA reads done) ----
  if (act) {
    #pragma unroll
    for (int k = 0; k < 8; ++k) red2[rg][cg*8+k] = cs[k];
  }
  __syncthreads();
  if (tid < 64) {
    float m = 0.f;
    if (tid < 56) {
      #pragma unroll
      for (int r = 0; r < 32; ++r) m += red2[r][tid];
    }
    muPart[((size_t)s*C_ + c)*64 + tid] = m;
  }
  __syncthreads();

  // ---- epilogue: S = P + Q + Q^T ----
  #pragma unroll
  for (int j = 0; j < 4; ++j) {
    #pragma unroll
    for (int e = 0; e < 4; ++e) {
      int r = 16*w + 4*lq + e, cc = 16*j + lr;
      Qbuf[r][cc] = accQ[j][e];
    }
  }
  __syncthreads();
  float* op = covPart + ((size_t)s*C_ + c)*DD_;
  #pragma unroll
  for (int j = 0; j < 4; ++j) {
    #pragma unroll
    for (int e = 0; e < 4; ++e) {
      int r = 16*w + 4*lq + e, cc = 16*j + lr;
      if (r < 56 && cc < 56) op[r*56 + cc] = accP[j][e] + accQ[j][e] + Qbuf[cc][r];
    }
  }
}

// Coupled Newton-Schulz via fp16-split MFMA, with fused cov finalization.
// which==0: covTr = covIn/cnt - muTrn x muTrn          -> sqrt    -> Sout
// which==1: covTest = sum(covPart)/M - mu x mu (jitter) -> invsqrt -> Zout ; writes muT
// Raw fp32 cov staged in LDS overlaid on the Th/Tl region (dead until first store_split,
// which fully rewrites cols 0..63; pad cols 64..71 are never read by mm_split).
__global__ __launch_bounds__(256) void k_ns(const float* __restrict__ covIn, const float* __restrict__ muTrn,
                                            const int* __restrict__ counter,
                                            const float* __restrict__ covPart, const float* __restrict__ muPart,
                                            float* __restrict__ Sout, float* __restrict__ Zout,
                                            float* __restrict__ muT) {
  __shared__ __align__(16) _Float16 mats[6][64][72];
  __shared__ float red[4];
  __shared__ float smu[64];
  int tid = threadIdx.x;
  int which = blockIdx.x & 1, c = blockIdx.x >> 1;
  typedef _Float16 (*mat_t)[72];
  mat_t Yh = mats[0], Yl = mats[1], Zh = mats[2], Zl = mats[3], Th = mats[4], Tl = mats[5];
  float (*Araw)[60] = (float(*)[60])&mats[4][0][0];   // 13440 B overlay (Th/Tl = 18432 B)

  // zero Y and Z mats only (incl. their pad cols); Th/Tl fully rewritten before first read
  { unsigned* z = (unsigned*)mats; for (int i = tid; i < 9216; i += 256) z[i] = 0u; }

  if (which == 0) {
    if (tid < 64) smu[tid] = (tid < 56) ? muTrn[c*56 + tid] : 0.f;
    __syncthreads();
    float icnt = 1.f / (float)counter[0];
    const float4* ci4 = (const float4*)(covIn + (size_t)c*DD_);
    for (int i4 = tid; i4 < 784; i4 += 256) {
      float4 v = ci4[i4];
      int r = i4 / 14, cg = (i4 % 14) * 4;
      float mr = smu[r];
      v.x = v.x*icnt - mr*smu[cg+0];
      v.y = v.y*icnt - mr*smu[cg+1];
      v.z = v.z*icnt - mr*smu[cg+2];
      v.w = v.w*icnt - mr*smu[cg+3];
      *(float4*)&Araw[r][cg] = v;
    }
  } else {
    if (tid < 64) {
      float m = 0.f;
      #pragma unroll
      for (int p2 = 0; p2 < 4; ++p2) m += muPart[((size_t)p2*C_ + c)*64 + tid];
      m *= (1.0f/M_);
      smu[tid] = m;
      muT[c*64 + tid] = m;
    }
    __syncthreads();
    const float4* cp4 = (const float4*)covPart;
    for (int i4 = tid; i4 < 784; i4 += 256) {
      float4 a = make_float4(0.f, 0.f, 0.f, 0.f);
      #pragma unroll
      for (int p2 = 0; p2 < 4; ++p2) {
        float4 v = cp4[((size_t)p2*C_ + c)*784 + i4];
        a.x += v.x; a.y += v.y; a.z += v.z; a.w += v.w;
      }
      int r = i4 / 14, cg = (i4 % 14) * 4;
      float mr = smu[r];
      a.x = a.x*(1.0f/M_) - mr*smu[cg+0];
      a.y = a.y*(1.0f/M_) - mr*smu[cg+1];
      a.z = a.z*(1.0f/M_) - mr*smu[cg+2];
      a.w = a.w*(1.0f/M_) - mr*smu[cg+3];
      if (r == cg+0) a.x *= 1.001f;
      if (r == cg+1) a.y *= 1.001f;
      if (r == cg+2) a.z *= 1.001f;
      if (r == cg+3) a.w *= 1.001f;
      *(float4*)&Araw[r][cg] = a;
    }
  }
  __syncthreads();

  // Frobenius norm from LDS
  float ss = 0.f;
  for (int i = tid; i < DD_; i += 256) { float v = Araw[i/56][i%56]; ss += v*v; }
  #pragma unroll
  for (int off = 32; off > 0; off >>= 1) ss += __shfl_down(ss, off, 64);
  if ((tid & 63) == 0) red[tid >> 6] = ss;
  __syncthreads();
  float s = sqrtf(red[0] + red[1] + red[2] + red[3]);
  float inv = 1.f / s;

  // Y0 = A/s (split), Z0 = I
  for (int i4 = tid; i4 < 784; i4 += 256) {
    int r = i4 / 14, cgx = (i4 % 14) * 4;
    float4 v = *(const float4*)&Araw[r][cgx];
    float f0 = v.x*inv, f1 = v.y*inv, f2 = v.z*inv, f3 = v.w*inv;
    v4h hh, ll;
    hh.x = (_Float16)f0; ll.x = (_Float16)(f0 - (float)hh.x);
    hh.y = (_Float16)f1; ll.y = (_Float16)(f1 - (float)hh.y);
    hh.z = (_Float16)f2; ll.z = (_Float16)(f2 - (float)hh.z);
    hh.w = (_Float16)f3; ll.w = (_Float16)(f3 - (float)hh.w);
    *(v4h*)&Yh[r][cgx] = hh;
    *(v4h*)&Yl[r][cgx] = ll;
  }
  if (tid < 56) Zh[tid][tid] = (_Float16)1.0f;
  __syncthreads();

  int lane = tid & 63, w = tid >> 6, lr = lane & 15, lq = lane >> 4;
  v4f zero4 = {0.f, 0.f, 0.f, 0.f};
  float rs = sqrtf(s);
  float fac = which ? (1.f/rs) : rs;
  float* outp = (which ? Zout : Sout) + (size_t)c*DD_;

  for (int it = 0; it < NS_ITERS; ++it) {
    v4f accW[4] = {zero4, zero4, zero4, zero4};
    mm_split_h(Zh, Zl, Yh, Yl, w, lr, lq, accW);
    v4f Tv[4];
    #pragma unroll
    for (int jt = 0; jt < 4; ++jt) {
      #pragma unroll
      for (int e = 0; e < 4; ++e) {
        float dv = (16*w + 4*lq + e == 16*jt + lr) ? 1.5f : 0.f;
        Tv[jt][e] = dv - 0.5f*accW[jt][e];
      }
    }
    store_split_h(Th, Tl, w, lr, lq, Tv);
    __syncthreads();
    if (it == NS_ITERS - 1) {
      v4f accF[4] = {zero4, zero4, zero4, zero4};
      if (which == 0) mm_split_h(Yh, Yl, Th, Tl, w, lr, lq, accF);
      else            mm_split_h(Th, Tl, Zh, Zl, w, lr, lq, accF);
      #pragma unroll
      for (int jt = 0; jt < 4; ++jt) {
        #pragma unroll
        for (int e = 0; e < 4; ++e) {
          int i = 16*w + 4*lq + e, j = 16*jt + lr;
          if (i < 56 && j < 56) outp[i*56 + j] = accF[jt][e] * fac;
        }
      }
    } else {
      v4f accY[4] = {zero4, zero4, zero4, zero4};
      v4f accZ[4] = {zero4, zero4, zero4, zero4};
      mm_split_h(Yh, Yl, Th, Tl, w, lr, lq, accY);
      mm_split_h(Th, Tl, Zh, Zl, w, lr, lq, accZ);
      __syncthreads();
      store_split_h(Yh, Yl, w, lr, lq, accY);
      store_split_h(Zh, Zl, w, lr, lq, accZ);
      __syncthreads();
    }
  }
}

// Tm[c] = Zi[c] @ S[c]  via fp16-split MFMA
__global__ __launch_bounds__(256) void k_tmap(const float* __restrict__ Zi, const float* __restrict__ Sm,
                                              float* __restrict__ Tm) {
  __shared__ __align__(16) _Float16 mats[4][64][72];
  int c = blockIdx.x, tid = threadIdx.x;
  typedef _Float16 (*mat_t)[72];
  mat_t Ah = mats[0], Al = mats[1], Bh = mats[2], Bl = mats[3];
  { unsigned* z = (unsigned*)mats; for (int i = tid; i < 9216; i += 256) z[i] = 0u; }
  __syncthreads();
  const float4* Z4 = (const float4*)(Zi + (size_t)c*DD_);
  const float4* S4 = (const float4*)(Sm + (size_t)c*DD_);
  for (int i4 = tid; i4 < 784; i4 += 256) {
    int r = i4 / 14, cgx = (i4 % 14) * 4;
    float4 v = Z4[i4];
    v4h hh, ll;
    hh.x = (_Float16)v.x; ll.x = (_Float16)(v.x - (float)hh.x);
    hh.y = (_Float16)v.y; ll.y = (_Float16)(v.y - (float)hh.y);
    hh.z = (_Float16)v.z; ll.z = (_Float16)(v.z - (float)hh.z);
    hh.w = (_Float16)v.w; ll.w = (_Float16)(v.w - (float)hh.w);
    *(v4h*)&Ah[r][cgx] = hh;
    *(v4h*)&Al[r][cgx] = ll;
    v = S4[i4];
    hh.x = (_Float16)v.x; ll.x = (_Float16)(v.x - (float)hh.x);
    hh.y = (_Float16)v.y; ll.y = (_Float16)(v.y - (float)hh.y);
    hh.z = (_Float16)v.z; ll.z = (_Float16)(v.z - (float)hh.z);
    hh.w = (_Float16)v.w; ll.w = (_Float16)(v.w - (float)hh.w);
    *(v4h*)&Bh[r][cgx] = hh;
    *(v4h*)&Bl[r][cgx] = ll;
  }
  __syncthreads();
  int lane = tid & 63, w = tid >> 6, lr = lane & 15, lq = lane >> 4;
  v4f zero4 = {0.f, 0.f, 0.f, 0.f};
  v4f acc[4] = {zero4, zero4, zero4, zero4};
  mm_split_h(Ah, Al, Bh, Bl, w, lr, lq, acc);
  float* op = Tm + (size_t)c*DD_;
  #pragma unroll
  for (int jt = 0; jt < 4; ++jt) {
    #pragma unroll
    for (int e = 0; e < 4; ++e) {
      int i = 16*w + 4*lq + e, j = 16*jt + lr;
      if (i < 56 && j < 56) op[i*56 + j] = acc[jt][e];
    }
  }
}

// 4 tiles per block: Y = (X - muT) @ T + muTrain via fp16 MFMA, fp32 accum.
// T staged once per block; next tile's X prefetched to regs under current MFMA.
__global__ __launch_bounds__(256) void k_apply(const _Float16* __restrict__ in, const float* __restrict__ muT,
                                               const float* __restrict__ Tmp, const float* __restrict__ muTrain,
                                               _Float16* __restrict__ out, int stage) {
  int b = blockIdx.x;
  int c = b >> 4, ng = b & 15;
  int n0 = ng * 4;
  __shared__ __align__(16) _Float16 Abf[64][72];   // X tile [m][k]
  __shared__ __align__(16) _Float16 Tt[64][72];    // T^T [f][k]
  __shared__ float Y[56][57];                      // result tile
  __shared__ float smu[64], smt[64];
  int tid = threadIdx.x;
  if (tid < 64) {
    smu[tid] = muT[c*64 + tid];
    smt[tid] = (tid < 56) ? muTrain[c*56 + tid] : 0.f;
  }
  if (tid < 128) {   // zero K-pad cols [56:64) once
    int row = tid & 63;
    _Float16 (*Mz)[72] = (tid < 64) ? Abf : Tt;
    *(float4*)&Mz[row][56] = make_float4(0.f, 0.f, 0.f, 0.f);
  }
  // T stage (once per block)
  const float4* t4 = (const float4*)(Tmp + (size_t)c*DD_);
  for (int i = tid; i < 784; i += 256) {
    float4 t = t4[i];
    int row = i / 14, cgx = (i % 14) * 4;
    Tt[cgx+0][row] = (_Float16)t.x;
    Tt[cgx+1][row] = (_Float16)t.y;
    Tt[cgx+2][row] = (_Float16)t.z;
    Tt[cgx+3][row] = (_Float16)t.w;
  }
  int l = tid & 63, w = tid >> 6;
  int lr = l & 15, lq = l >> 4;
  v4f zero4 = {0.f, 0.f, 0.f, 0.f};
  const v8h* p8base = (const v8h*)(in + (size_t)c*PL_);

  v8h preA[2], preB[2];
  {
    const v8h* p8 = p8base + (size_t)n0*392;
    #pragma unroll
    for (int u = 0; u < 2; ++u) { int i = tid + 256*u; if (i < 392) preA[u] = p8[i]; }
  }
  for (int t = 0; t < 4; ++t) {
    #pragma unroll
    for (int u = 0; u < 2; ++u) {
      int i = tid + 256*u;
      if (i < 392) {
        int row = i / 7, cg = i % 7;
        v8h pk;
        #pragma unroll
        for (int k = 0; k < 8; ++k) pk[k] = (_Float16)((float)preA[u][k] - smu[cg*8+k]);
        *(v8h*)&Abf[row][cg*8] = pk;
      }
    }
    __syncthreads();
    if (t < 3) {   // prefetch tile t+1 (latency hides under MFMA)
      const v8h* p8 = p8base + (size_t)(n0+t+1)*392;
      #pragma unroll
      for (int u = 0; u < 2; ++u) { int i = tid + 256*u; if (i < 392) preB[u] = p8[i]; }
    }
    v4f acc[4] = {zero4, zero4, zero4, zero4};
    #pragma unroll
    for (int s = 0; s < 2; ++s) {
      int kb = 32*s + 8*lq;
      v8h a = *(const v8h*)&Abf[16*w + lr][kb];
      #pragma unroll
      for (int j = 0; j < 4; ++j) {
        v8h bb = *(const v8h*)&Tt[16*j + lr][kb];
        acc[j] = __builtin_amdgcn_mfma_f32_16x16x32_f16(a, bb, acc[j], 0, 0, 0);
      }
    }
    __syncthreads();
    #pragma unroll
    for (int j = 0; j < 4; ++j) {
      #pragma unroll
      for (int e = 0; e < 4; ++e) {
        int r = 16*w + 4*lq + e, cc = 16*j + lr;
        if (r < 56 && cc < 56) Y[r][cc] = acc[j][e] + smt[cc];
      }
    }
    __syncthreads();
    _Float16* o16 = out + (size_t)c*PL_ + (size_t)(n0+t)*3136;
    if (stage == 1) {
      for (int i = tid; i < 392; i += 256) {
        int h = i / 7, wg = i % 7;
        v8h o;
        #pragma unroll
        for (int k = 0; k < 8; ++k) o[k] = (_Float16)Y[wg*8+k][h];
        *(v8h*)&o16[h*56 + wg*8] = o;
      }
    } else {
      for (int i = tid; i < 392; i += 256) {
        int h = i / 7, wg = i % 7;
        v8h o;
        #pragma unroll
        for (int k = 0; k < 8; ++k) o[k] = (_Float16)Y[h][wg*8+k];
        *(v8h*)&o16[h*56 + wg*8] = o;
      }
    }
    preA[0] = preB[0]; preA[1] = preB[1];
  }
}

// A2 (c, n, h, w) fp16 -> out (n, h, w, c) fp32. Group of 4 nh per block.
__global__ __launch_bounds__(256) void k_tout(const _Float16* __restrict__ A2, float* __restrict__ out) {
  int b = blockIdx.x;
  int cchunk = b & 3, g = b >> 2;
  int c0 = cchunk * 64;
  int nh0 = g * 4;
  __shared__ _Float16 t[4][56][66];   // [mloc][w][cc]
  int tid = threadIdx.x;
  #pragma unroll
  for (int it = 0; it < 7; ++it) {
    int j = tid + 256*it;
    int q = j / 7, wg = j % 7;
    int cc = q >> 2, mloc = q & 3;
    v8h v = *(const v8h*)&A2[(size_t)(c0+cc)*PL_ + (size_t)(nh0+mloc)*56 + wg*8];
    #pragma unroll
    for (int k = 0; k < 8; ++k) t[mloc][wg*8+k][cc] = v[k];
  }
  __syncthreads();
  float4* o4 = (float4*)out;
  #pragma unroll
  for (int it = 0; it < 14; ++it) {
    int i = tid + 256*it;
    int mloc = i / 896, r = i % 896;
    int w = r >> 4, cg = r & 15;
    float4 o;
    o.x = (float)t[mloc][w][4*cg+0];
    o.y = (float)t[mloc][w][4*cg+1];
    o.z = (float)t[mloc][w][4*cg+2];
    o.w = (float)t[mloc][w][4*cg+3];
    o4[((size_t)(nh0+mloc)*56 + w)*64 + (c0>>2) + cg] = o;
  }
}

extern "C" void kernel_launch(void* const* d_in, const int* in_sizes, int n_in,
                              void* d_out, int out_size, void* d_ws, size_t ws_size,
                              hipStream_t stream) {
  (void)in_sizes; (void)n_in; (void)out_size;
  const float* x    = (const float*)d_in[0];
  const float* covH = (const float*)d_in[1];
  const float* muH  = (const float*)d_in[2];
  const float* covW = (const float*)d_in[3];
  const float* muW  = (const float*)d_in[4];
  const int*   cnt  = (const int*)d_in[5];
  float* out = (float*)d_out;

  char* ws = (char*)d_ws;
  size_t off = 0;
  auto allocB = [&](size_t nbytes) {
    void* p = ws + off;
    off += ((nbytes + 255) / 256) * 256;
    return p;
  };
  _Float16* A16a  = (_Float16*)allocB((size_t)C_ * PL_ * 2);
  _Float16* A16b  = (_Float16*)allocB((size_t)C_ * PL_ * 2);
  float* covPart  = (float*)allocB((size_t)4 * C_ * DD_ * 4);
  float* muPart   = (float*)allocB((size_t)4 * C_ * 64 * 4);
  float* Sm       = (float*)allocB((size_t)C_ * DD_ * 4);
  float* Zim      = (float*)allocB((size_t)C_ * DD_ * 4);
  float* Tm       = (float*)allocB((size_t)C_ * DD_ * 4);
  float* muT      = (float*)allocB((size_t)C_ * 64 * 4);
  if (off > ws_size) return;

  dim3 blk(256);

  k_tin<<<dim3(4 * (M_/4)), blk, 0, stream>>>(x, A16a);

  // ---- stage 1 (H axis) ----
  k_stats<<<dim3(1024), blk, 0, stream>>>(A16a, muPart, covPart);
  k_ns   <<<dim3(512),  blk, 0, stream>>>(covH, muH, cnt, covPart, muPart, Sm, Zim, muT);
  k_tmap <<<dim3(256),  blk, 0, stream>>>(Zim, Sm, Tm);
  k_apply<<<dim3(4096), blk, 0, stream>>>(A16a, muT, Tm, muH, A16b, 1);

  // ---- stage 2 (W axis) ----
  k_stats<<<dim3(1024), blk, 0, stream>>>(A16b, muPart, covPart);
  k_ns   <<<dim3(512),  blk, 0, stream>>>(covW, muW, cnt, covPart, muPart, Sm, Zim, muT);
  k_tmap <<<dim3(256),  blk, 0, stream>>>(Zim, Sm, Tm);
  k_apply<<<dim3(4096), blk, 0, stream>>>(A16b, muT, Tm, muW, A16a, 2);

  k_tout<<<dim3(4 * (M_/4)), blk, 0, stream>>>(A16a, out);
}